// Round 16
// baseline (123.862 us; speedup 1.0000x reference)
//
#include <hip/hip_runtime.h>
#include <hip/hip_bf16.h>
#include <stdint.h>

#define T_LEN 8192
#define DIN   1024
#define DOUT  1024
#define TRACE 64
#define CTX   16
#define KTOT  3072      // DIN + 2*TRACE*CTX
#define CH    64        // scan chunk length
#define NCHUNK 128      // T_LEN / CH

#define AS1 __attribute__((address_space(1)))
#define AS3 __attribute__((address_space(3)))

// Compile-time-fenced barrier (r9 race fix: intrinsic barrier is not a compiler fence).
#define BAR() asm volatile("s_barrier" ::: "memory")

using bf16 = __hip_bfloat16;
typedef __attribute__((ext_vector_type(4))) float f32x4;
typedef __attribute__((ext_vector_type(8))) short s16x8;

__device__ __forceinline__ void pack4(const float4 v, void* dst) {
    union { bf16 h[4]; uint2 u; } pk;
    pk.h[0] = __float2bfloat16(v.x); pk.h[1] = __float2bfloat16(v.y);
    pk.h[2] = __float2bfloat16(v.z); pk.h[3] = __float2bfloat16(v.w);
    *(uint2*)dst = pk.u;
}

__device__ __forceinline__ uint4 pack8(const float4 a, const float4 b) {
    union { bf16 h[8]; uint4 u; } pk;
    pk.h[0] = __float2bfloat16(a.x); pk.h[1] = __float2bfloat16(a.y);
    pk.h[2] = __float2bfloat16(a.z); pk.h[3] = __float2bfloat16(a.w);
    pk.h[4] = __float2bfloat16(b.x); pk.h[5] = __float2bfloat16(b.y);
    pk.h[6] = __float2bfloat16(b.z); pk.h[7] = __float2bfloat16(b.w);
    return pk.u;
}

// ---------------- tiny: W_pre -> Wp bf16 (x rides inside pre_scan1 now) ----------------
__global__ void cvt_wp(const float* __restrict__ Wpre, bf16* __restrict__ Wp) {
    int idx = blockIdx.x * 256 + threadIdx.x;   // 16384 quads
    int r = idx >> 8, c4 = (idx & 255) << 2;
    pack4(*(const float4*)(Wpre + (size_t)r * 1024 + c4), Wp + (size_t)r * 1024 + c4);
}

// ---------------- fused: x-cvt pre-loop + pre-GEMM + scan phase 1 ----------------
// Pre-loop: block converts its 64 rows x(f32) -> A(bf16) coalesced (8 f32/thread/iter),
// then the unchanged r10 K-loop gload_lds-stages A back (L2-hot, same XCD).
__global__ __launch_bounds__(256) void pre_scan1(
    const float* __restrict__ x,    // [8192][1024] f32
    const bf16* __restrict__ Wp,    // [64][1024]
    bf16* __restrict__ A,           // [8192][KTOT] — x part written + re-read here
    const float* __restrict__ bpre,
    const int* __restrict__ start,
    const float* __restrict__ a, const float* __restrict__ bfreq,
    float* __restrict__ pre_raw,    // [8192][64]
    float2* __restrict__ local_end, // [128][1024]
    int* __restrict__ reset_any) {  // [128]
    __shared__ short As[2][64 * 32];
    __shared__ short Bs[2][64 * 32];
    __shared__ float pn[CH][TRACE + 1];
    __shared__ float rn[CH];
    __shared__ int sf[CH];
    const int tid = threadIdx.x, lane = tid & 63, wv = tid >> 6;
    const int row0 = blockIdx.x * 64;
    const int l4 = lane >> 2, c8 = (lane & 3) * 8;

    // ---- pre-loop: convert 64 rows x -> A (8192 groups of 8 f32; 32 iters/thread) ----
    for (int i = 0; i < 32; ++i) {
        int idx = i * 256 + tid;            // 0..8191
        int r = idx >> 7, cc = (idx & 127) << 3;
        const float* src = x + (size_t)(row0 + r) * 1024 + cc;
        float4 v0 = *(const float4*)(src);
        float4 v1 = *(const float4*)(src + 4);
        *(uint4*)(A + (size_t)(row0 + r) * KTOT + cc) = pack8(v0, v1);
    }
    __syncthreads();   // compiler drains vmcnt before barrier -> stores visible via L2

    auto stage = [&](int kt, int buf) {
        int r = wv * 16 + l4;
        const bf16* ga = A + (size_t)(row0 + r) * KTOT + kt * 32 + c8;
        const bf16* gb = Wp + (size_t)r * 1024 + kt * 32 + c8;
        __builtin_amdgcn_global_load_lds(
            (const AS1 void*)ga, (AS3 void*)&As[buf][wv * 512], 16, 0, 0);
        __builtin_amdgcn_global_load_lds(
            (const AS1 void*)gb, (AS3 void*)&Bs[buf][wv * 512], 16, 0, 0);
    };

    f32x4 acc[4];
#pragma unroll
    for (int j = 0; j < 4; ++j) acc[j] = (f32x4)0.0f;

    stage(0, 0);
    __syncthreads();
    int buf = 0;
    const int lr = lane & 15, lk = (lane >> 4) * 8;
    for (int kt = 0; kt < 32; ++kt) {
        if (kt + 1 < 32) stage(kt + 1, buf ^ 1);
        s16x8 af = *(const s16x8*)&As[buf][(wv * 16 + lr) * 32 + lk];
        s16x8 bfr[4];
#pragma unroll
        for (int j = 0; j < 4; ++j)
            bfr[j] = *(const s16x8*)&Bs[buf][(j * 16 + lr) * 32 + lk];
#pragma unroll
        for (int j = 0; j < 4; ++j)
            acc[j] = __builtin_amdgcn_mfma_f32_16x16x32_bf16(af, bfr[j], acc[j], 0, 0, 0);
        __syncthreads();
        buf ^= 1;
    }
    const int lg = lane >> 4;
#pragma unroll
    for (int j = 0; j < 4; ++j) {
        int col = j * 16 + lr;
        float bias = bpre[col];
#pragma unroll
        for (int r = 0; r < 4; ++r) {
            int rl = wv * 16 + lg * 4 + r;
            float v = acc[j][r] + bias;
            pn[rl][col] = v;
            pre_raw[(size_t)(row0 + rl) * TRACE + col] = v;
        }
    }
    if (tid < CH) sf[tid] = start[row0 + tid];
    __syncthreads();
    if (tid < CH) {
        float s = 0.f;
#pragma unroll
        for (int m = 0; m < TRACE; ++m) { float v = pn[tid][m]; s += v * v; }
        rn[tid] = 1.0f / (1e-6f + sqrtf(s));
        int any = __any(sf[tid] != 0);
        if (tid == 0) reset_any[blockIdx.x] = any;
    }
    __syncthreads();
#pragma unroll
    for (int q = 0; q < 4; ++q) {
        int pair = tid + q * 256;
        int m = pair >> 4, c = pair & 15;
        float am = a[m], th = bfreq[c];
        float e = expf(-fabsf(am));
        float sn, cs; sincosf(th, &sn, &cs);
        float gr = e * cs, gi = e * sn;
        float sre = 0.f, sim = 0.f;
        for (int r = 0; r < CH; ++r) {
            float p = pn[r][m] * rn[r];
            if (sf[r]) { sre = p; sim = 0.f; }
            else { float t = gr * sre - gi * sim + p; sim = gr * sim + gi * sre; sre = t; }
        }
        local_end[(size_t)blockIdx.x * 1024 + pair] = make_float2(sre, sim);
    }
}

// ---------------- scan phase 2 (blocks 0-15) + weight cvt (blocks 16+) ----------------
__global__ void scan_phase2w(const float2* __restrict__ local_end, const int* __restrict__ reset_any,
                             const float* __restrict__ state_re, const float* __restrict__ state_im,
                             const float* __restrict__ a, const float* __restrict__ bfreq,
                             float2* __restrict__ carry_in, float* __restrict__ out_tail, int tail_n,
                             const float* __restrict__ Wsk, const float* __restrict__ Wmx,
                             bf16* __restrict__ Bc) {
    if (blockIdx.x >= 16) {
        int idx = (blockIdx.x - 16) * 256 + threadIdx.x;  // 786432 quads
        if (idx < 262144) {                // W_skip: 1024x1024 -> Bc (coff 0)
            int r = idx >> 8, c4 = (idx & 255) << 2;
            pack4(*(const float4*)(Wsk + (size_t)r * 1024 + c4), Bc + (size_t)r * KTOT + c4);
        } else {                           // W_mix: 1024x2048 -> Bc (coff 1024)
            int i = idx - 262144;
            int r = i >> 9, c4 = (i & 511) << 2;
            pack4(*(const float4*)(Wmx + (size_t)r * 2048 + c4), Bc + (size_t)r * KTOT + 1024 + c4);
        }
        return;
    }
    if (threadIdx.x >= 64) return;
    const int pair = blockIdx.x * 64 + threadIdx.x;  // 16*64 = 1024
    const int m = pair >> 4, c = pair & 15;
    float am = a[m], th = bfreq[c];
    float e = expf(-64.f * fabsf(am));
    float sn, cs; sincosf(64.f * th, &sn, &cs);
    float gr = e * cs, gi = e * sn;
    float cre = state_re[pair], cim = state_im[pair];

    float2 pf[8]; int rsv[8];
#pragma unroll
    for (int j = 0; j < 8; ++j) { pf[j] = local_end[(size_t)j * 1024 + pair]; rsv[j] = reset_any[j]; }
    for (int kb = 0; kb < NCHUNK; kb += 8) {
        float2 cur[8]; int rs[8];
#pragma unroll
        for (int j = 0; j < 8; ++j) { cur[j] = pf[j]; rs[j] = rsv[j]; }
        if (kb + 8 < NCHUNK) {
#pragma unroll
            for (int j = 0; j < 8; ++j) {
                pf[j]  = local_end[(size_t)(kb + 8 + j) * 1024 + pair];
                rsv[j] = reset_any[kb + 8 + j];
            }
        }
#pragma unroll
        for (int j = 0; j < 8; ++j) {
            carry_in[(size_t)(kb + j) * 1024 + pair] = make_float2(cre, cim);
            if (rs[j]) { cre = cur[j].x; cim = cur[j].y; }
            else {
                float t = gr * cre - gi * cim + cur[j].x;
                cim = gr * cim + gi * cre + cur[j].y;
                cre = t;
            }
        }
    }
    if (pair < tail_n)        out_tail[pair]        = cre;
    if (1024 + pair < tail_n) out_tail[1024 + pair] = cim;
}

// ---------------- scan phase 3: 256 blocks — chunk k = b>>1, pair-half h = b&1 ----------------
__global__ void scan_phase3(const float* __restrict__ pre_raw, const int* __restrict__ start,
                            const float* __restrict__ a, const float* __restrict__ bfreq,
                            const float2* __restrict__ carry_in, bf16* __restrict__ A) {
    __shared__ float pn[CH][TRACE + 1];
    __shared__ float rn[CH];
    __shared__ int sf[CH];
    const int k = blockIdx.x >> 1, h = blockIdx.x & 1, tid = threadIdx.x;
    for (int idx = tid; idx < CH * TRACE; idx += 256) {
        int r = idx >> 6, m = idx & 63;
        pn[r][m] = pre_raw[(size_t)(k * CH + r) * TRACE + m];
    }
    if (tid < CH) sf[tid] = start[k * CH + tid];
    __syncthreads();
    if (tid < CH) {
        float s = 0.f;
#pragma unroll
        for (int m = 0; m < TRACE; ++m) { float v = pn[tid][m]; s += v * v; }
        rn[tid] = 1.0f / (1e-6f + sqrtf(s));
    }
    __syncthreads();
    {
        int p0 = h * 512 + tid * 2;           // this block covers pairs [h*512, h*512+512)
        int m = p0 >> 4, c0 = p0 & 15;
        float am = a[m];
        float e = expf(-fabsf(am));
        float sn0, cs0, sn1, cs1;
        sincosf(bfreq[c0], &sn0, &cs0);
        sincosf(bfreq[c0 + 1], &sn1, &cs1);
        float gr0 = e * cs0, gi0 = e * sn0;
        float gr1 = e * cs1, gi1 = e * sn1;
        float4 ci = *(const float4*)&carry_in[(size_t)k * 1024 + p0];
        float sre0 = ci.x, sim0 = ci.y, sre1 = ci.z, sim1 = ci.w;
        for (int r = 0; r < CH; ++r) {
            float p = pn[r][m] * rn[r];
            if (sf[r]) { sre0 = p; sim0 = 0.f; sre1 = p; sim1 = 0.f; }
            else {
                float t0 = gr0 * sre0 - gi0 * sim0 + p; sim0 = gr0 * sim0 + gi0 * sre0; sre0 = t0;
                float t1 = gr1 * sre1 - gi1 * sim1 + p; sim1 = gr1 * sim1 + gi1 * sre1; sre1 = t1;
            }
            size_t off = (size_t)(k * CH + r) * KTOT + 1024 + m * 32;
            union { bf16 h2[2]; uint32_t u; } pr, pi;
            pr.h2[0] = __float2bfloat16(sre0); pr.h2[1] = __float2bfloat16(sre1);
            pi.h2[0] = __float2bfloat16(sim0); pi.h2[1] = __float2bfloat16(sim1);
            *(uint32_t*)(A + off + c0)      = pr.u;
            *(uint32_t*)(A + off + 16 + c0) = pi.u;
        }
    }
}

// ---------------- main GEMM (unchanged r10 structure) ----------------
// BM=256 BN=128 BK=64, 512 thr (8 waves 4Mx2N, 64x64/wave), grid 256 = 1 block/CU.
// 2 phases per K-tile, 3 LDS buffers:
//   phase = { ds_reads (cur) ; stage (tile u+2) ; BAR ; setprio(1) 16 MFMA setprio(0) ;
//             [vmcnt(6) at tile end] ; lgkmcnt(0) ; BAR }
__global__ __launch_bounds__(512) void gemm_main(const bf16* __restrict__ A,  // [8192][3072]
                                                 const bf16* __restrict__ B,  // [1024][3072]
                                                 const float* __restrict__ bskip,
                                                 const float* __restrict__ bmix,
                                                 float* __restrict__ out) {   // [8192][1024]
    __shared__ short As[3][256 * 64];   // 96 KB
    __shared__ short Bs[3][128 * 64];   // 48 KB
    const int tid = threadIdx.x;
    const int lane = tid & 63, wv = tid >> 6;
    const int wm = wv >> 1, wn = wv & 1;
    const int wg = blockIdx.x;
    const int xcd = wg & 7, bidx = wg >> 3;          // HW round-robins wg across XCDs
    const int row0 = (xcd * 4 + (bidx >> 3)) * 256;  // 32 row tiles
    const int col0 = (bidx & 7) * 128;               // 8 col tiles

    const int rl8 = lane >> 3;
    const int u8  = lane & 7;
    const int ksw = (u8 ^ rl8) << 3;

    auto stageBatch = [&](int su, int bd, int sb) {
#pragma unroll
        for (int jj = 0; jj < 2; ++jj) {
            int j = sb * 2 + jj;
            int r = wv * 32 + j * 8 + rl8;
            const bf16* ga = A + (size_t)(row0 + r) * KTOT + su * 64 + ksw;
            __builtin_amdgcn_global_load_lds((const AS1 void*)ga,
                (AS3 void*)&As[bd][(wv * 32 + j * 8) * 64], 16, 0, 0);
        }
        int rb = wv * 16 + sb * 8 + rl8;
        const bf16* gb = B + (size_t)(col0 + rb) * KTOT + su * 64 + ksw;
        __builtin_amdgcn_global_load_lds((const AS1 void*)gb,
            (AS3 void*)&Bs[bd][(wv * 16 + sb * 8) * 64], 16, 0, 0);
    };

    f32x4 acc[4][4];
#pragma unroll
    for (int i = 0; i < 4; ++i)
#pragma unroll
        for (int j = 0; j < 4; ++j) acc[i][j] = (f32x4)0.0f;

    const int lr = lane & 15, hi = lane >> 4;
    const int sw0 = ((0 + hi) ^ (lr & 7)) << 3;
    const int sw1 = ((4 + hi) ^ (lr & 7)) << 3;

    s16x8 af[4][2], bfr[4][2];

    auto phase = [&](int bc, int h, int su, int bd, int vm) {
        if (h == 0) {
#pragma unroll
            for (int i = 0; i < 4; ++i) {
                af[i][0] = *(const s16x8*)&As[bc][(wm * 64 + i * 16 + lr) * 64 + sw0];
                af[i][1] = *(const s16x8*)&As[bc][(wm * 64 + i * 16 + lr) * 64 + sw1];
            }
#pragma unroll
            for (int j = 0; j < 2; ++j) {
                bfr[j][0] = *(const s16x8*)&Bs[bc][(wn * 64 + j * 16 + lr) * 64 + sw0];
                bfr[j][1] = *(const s16x8*)&Bs[bc][(wn * 64 + j * 16 + lr) * 64 + sw1];
            }
        } else {
#pragma unroll
            for (int j = 2; j < 4; ++j) {
                bfr[j][0] = *(const s16x8*)&Bs[bc][(wn * 64 + j * 16 + lr) * 64 + sw0];
                bfr[j][1] = *(const s16x8*)&Bs[bc][(wn * 64 + j * 16 + lr) * 64 + sw1];
            }
        }
        if (su >= 0) stageBatch(su, bd, h);
        BAR();
        __builtin_amdgcn_s_setprio(1);
#pragma unroll
        for (int kk = 0; kk < 2; ++kk)
#pragma unroll
            for (int i = 0; i < 4; ++i)
#pragma unroll
                for (int jj = 0; jj < 2; ++jj) {
                    int j = h * 2 + jj;
                    acc[i][j] = __builtin_amdgcn_mfma_f32_16x16x32_bf16(af[i][kk], bfr[j][kk], acc[i][j], 0, 0, 0);
                }
        __builtin_amdgcn_s_setprio(0);
        if (vm == 6)      asm volatile("s_waitcnt vmcnt(6)" ::: "memory");
        else if (vm == 0) asm volatile("s_waitcnt vmcnt(0)" ::: "memory");
        asm volatile("s_waitcnt lgkmcnt(0)" ::: "memory");
        BAR();
    };

    stageBatch(0, 0, 0); stageBatch(0, 0, 1);
    stageBatch(1, 1, 0); stageBatch(1, 1, 1);
    asm volatile("s_waitcnt vmcnt(6)" ::: "memory");
    BAR();

    for (int t = 0; t < 15; ++t) {
        int u0 = 3 * t;
        phase(0, 0, u0 + 2, 2, -1);
        phase(0, 1, u0 + 2, 2,  6);
        phase(1, 0, u0 + 3, 0, -1);
        phase(1, 1, u0 + 3, 0,  6);
        phase(2, 0, u0 + 4, 1, -1);
        phase(2, 1, u0 + 4, 1,  6);
    }
    phase(0, 0, 47, 2, -1);
    phase(0, 1, 47, 2,  6);
    phase(1, 0, -1, 0, -1);
    phase(1, 1, -1, 0,  0);
    phase(2, 0, -1, 0, -1);
    phase(2, 1, -1, 0, -1);

    const int lg = lane >> 4;
#pragma unroll
    for (int j = 0; j < 4; ++j) {
        int col = col0 + wn * 64 + j * 16 + lr;
        float bias = bskip[col] + bmix[col];
#pragma unroll
        for (int i = 0; i < 4; ++i) {
            int rbase = row0 + wm * 64 + i * 16 + lg * 4;
#pragma unroll
            for (int r = 0; r < 4; ++r)
                out[(size_t)(rbase + r) * DOUT + col] = acc[i][j][r] + bias;
        }
    }
}

extern "C" void kernel_launch(void* const* d_in, const int* in_sizes, int n_in,
                              void* d_out, int out_size, void* d_ws, size_t ws_size,
                              hipStream_t stream) {
    const float* x        = (const float*)d_in[0];
    const float* state_re = (const float*)d_in[1];
    const float* state_im = (const float*)d_in[2];
    const int*   start    = (const int*)d_in[3];
    const float* W_pre    = (const float*)d_in[5];
    const float* b_pre    = (const float*)d_in[6];
    const float* W_skip   = (const float*)d_in[7];
    const float* b_skip   = (const float*)d_in[8];
    const float* W_mix    = (const float*)d_in[9];
    const float* b_mix    = (const float*)d_in[10];
    const float* a_dec    = (const float*)d_in[11];
    const float* b_freq   = (const float*)d_in[12];

    uint8_t* ws = (uint8_t*)d_ws;
    bf16*  A         = (bf16*)(ws);                 // 50331648
    bf16*  Bc        = (bf16*)(ws + 50331648);      // 6291456
    bf16*  Wp        = (bf16*)(ws + 56623104);      // 131072
    float* pre_raw   = (float*)(ws + 56754176);     // 2097152
    float2* local_end= (float2*)(ws + 58851328);    // 1048576
    float2* carry_in = (float2*)(ws + 59899904);    // 1048576
    int*   reset_any = (int*)(ws + 60948480);       // 512

    cvt_wp<<<dim3(64), 256, 0, stream>>>(W_pre, Wp);

    pre_scan1<<<dim3(NCHUNK), 256, 0, stream>>>(x, Wp, A, b_pre, start, a_dec, b_freq,
                                                pre_raw, local_end, reset_any);
    int tail_n = out_size - 8192 * 1024;
    if (tail_n < 0) tail_n = 0;
    if (tail_n > 2048) tail_n = 2048;
    scan_phase2w<<<dim3(16 + 3072), 256, 0, stream>>>(local_end, reset_any, state_re, state_im,
                                                      a_dec, b_freq, carry_in,
                                                      (float*)d_out + 8192 * 1024, tail_n,
                                                      W_skip, W_mix, Bc);
    scan_phase3<<<dim3(2 * NCHUNK), 256, 0, stream>>>(pre_raw, start, a_dec, b_freq, carry_in, A);

    gemm_main<<<dim3(256), 512, 0, stream>>>(A, Bc, b_skip, b_mix, (float*)d_out);
}

// Round 17
// 119.388 us; speedup vs baseline: 1.0375x; 1.0375x over previous
//
#include <hip/hip_runtime.h>
#include <hip/hip_bf16.h>
#include <stdint.h>

#define T_LEN 8192
#define DIN   1024
#define DOUT  1024
#define TRACE 64
#define CTX   16
#define KTOT  3072      // DIN + 2*TRACE*CTX
#define CH    64        // scan chunk length
#define NCHUNK 128      // T_LEN / CH

#define AS1 __attribute__((address_space(1)))
#define AS3 __attribute__((address_space(3)))

// Compile-time-fenced barrier (r9 race fix: intrinsic barrier is not a compiler fence).
#define BAR() asm volatile("s_barrier" ::: "memory")

using bf16 = __hip_bfloat16;
typedef __attribute__((ext_vector_type(4))) float f32x4;
typedef __attribute__((ext_vector_type(8))) short s16x8;

__device__ __forceinline__ void pack4(const float4 v, void* dst) {
    union { bf16 h[4]; uint2 u; } pk;
    pk.h[0] = __float2bfloat16(v.x); pk.h[1] = __float2bfloat16(v.y);
    pk.h[2] = __float2bfloat16(v.z); pk.h[3] = __float2bfloat16(v.w);
    *(uint2*)dst = pk.u;
}

// ---------------- f32 -> bf16: x and W_pre only (weights ride phase2w) ----------------
__global__ void cvt_x(const float* __restrict__ x, const float* __restrict__ Wpre,
                      bf16* __restrict__ A, bf16* __restrict__ Wp) {
    int idx = blockIdx.x * 256 + threadIdx.x;
    if (idx < 2097152) {                       // x: 8192x1024 -> A (ld 3072)
        int r = idx >> 8, c4 = (idx & 255) << 2;
        pack4(*(const float4*)(x + (size_t)r * 1024 + c4), A + (size_t)r * KTOT + c4);
    } else if (idx < 2113536) {                // W_pre: 64x1024 -> Wp (ld 1024)
        int i = idx - 2097152;
        int r = i >> 8, c4 = (i & 255) << 2;
        pack4(*(const float4*)(Wpre + (size_t)r * 1024 + c4), Wp + (size_t)r * 1024 + c4);
    }
}

// ---------------- fused pre-GEMM + scan phase 1 (r10/r15 version) ----------------
__global__ __launch_bounds__(256) void pre_scan1(
    const bf16* __restrict__ A,     // [8192][KTOT], x part (k<1024)
    const bf16* __restrict__ Wp,    // [64][1024]
    const float* __restrict__ bpre,
    const int* __restrict__ start,
    const float* __restrict__ a, const float* __restrict__ bfreq,
    float* __restrict__ pre_raw,    // [8192][64]
    float2* __restrict__ local_end, // [128][1024]
    int* __restrict__ reset_any) {  // [128]
    __shared__ short As[2][64 * 32];
    __shared__ short Bs[2][64 * 32];
    __shared__ float pn[CH][TRACE + 1];
    __shared__ float rn[CH];
    __shared__ int sf[CH];
    const int tid = threadIdx.x, lane = tid & 63, wv = tid >> 6;
    const int row0 = blockIdx.x * 64;
    const int l4 = lane >> 2, c8 = (lane & 3) * 8;

    auto stage = [&](int kt, int buf) {
        int r = wv * 16 + l4;
        const bf16* ga = A + (size_t)(row0 + r) * KTOT + kt * 32 + c8;
        const bf16* gb = Wp + (size_t)r * 1024 + kt * 32 + c8;
        __builtin_amdgcn_global_load_lds(
            (const AS1 void*)ga, (AS3 void*)&As[buf][wv * 512], 16, 0, 0);
        __builtin_amdgcn_global_load_lds(
            (const AS1 void*)gb, (AS3 void*)&Bs[buf][wv * 512], 16, 0, 0);
    };

    f32x4 acc[4];
#pragma unroll
    for (int j = 0; j < 4; ++j) acc[j] = (f32x4)0.0f;

    stage(0, 0);
    __syncthreads();
    int buf = 0;
    const int lr = lane & 15, lk = (lane >> 4) * 8;
    for (int kt = 0; kt < 32; ++kt) {
        if (kt + 1 < 32) stage(kt + 1, buf ^ 1);
        s16x8 af = *(const s16x8*)&As[buf][(wv * 16 + lr) * 32 + lk];
        s16x8 bfr[4];
#pragma unroll
        for (int j = 0; j < 4; ++j)
            bfr[j] = *(const s16x8*)&Bs[buf][(j * 16 + lr) * 32 + lk];
#pragma unroll
        for (int j = 0; j < 4; ++j)
            acc[j] = __builtin_amdgcn_mfma_f32_16x16x32_bf16(af, bfr[j], acc[j], 0, 0, 0);
        __syncthreads();
        buf ^= 1;
    }
    const int lg = lane >> 4;
#pragma unroll
    for (int j = 0; j < 4; ++j) {
        int col = j * 16 + lr;
        float bias = bpre[col];
#pragma unroll
        for (int r = 0; r < 4; ++r) {
            int rl = wv * 16 + lg * 4 + r;
            float v = acc[j][r] + bias;
            pn[rl][col] = v;
            pre_raw[(size_t)(row0 + rl) * TRACE + col] = v;
        }
    }
    if (tid < CH) sf[tid] = start[row0 + tid];
    __syncthreads();
    if (tid < CH) {
        float s = 0.f;
#pragma unroll
        for (int m = 0; m < TRACE; ++m) { float v = pn[tid][m]; s += v * v; }
        rn[tid] = 1.0f / (1e-6f + sqrtf(s));
        int any = __any(sf[tid] != 0);
        if (tid == 0) reset_any[blockIdx.x] = any;
    }
    __syncthreads();
#pragma unroll
    for (int q = 0; q < 4; ++q) {
        int pair = tid + q * 256;
        int m = pair >> 4, c = pair & 15;
        float am = a[m], th = bfreq[c];
        float e = expf(-fabsf(am));
        float sn, cs; sincosf(th, &sn, &cs);
        float gr = e * cs, gi = e * sn;
        float sre = 0.f, sim = 0.f;
        for (int r = 0; r < CH; ++r) {
            float p = pn[r][m] * rn[r];
            if (sf[r]) { sre = p; sim = 0.f; }
            else { float t = gr * sre - gi * sim + p; sim = gr * sim + gi * sre; sre = t; }
        }
        local_end[(size_t)blockIdx.x * 1024 + pair] = make_float2(sre, sim);
    }
}

// ---------------- scan phase 2 (blocks 0-15) + weight cvt (blocks 16+) ----------------
__global__ void scan_phase2w(const float2* __restrict__ local_end, const int* __restrict__ reset_any,
                             const float* __restrict__ state_re, const float* __restrict__ state_im,
                             const float* __restrict__ a, const float* __restrict__ bfreq,
                             float2* __restrict__ carry_in, float* __restrict__ out_tail, int tail_n,
                             const float* __restrict__ Wsk, const float* __restrict__ Wmx,
                             bf16* __restrict__ Bc) {
    if (blockIdx.x >= 16) {
        int idx = (blockIdx.x - 16) * 256 + threadIdx.x;  // 786432 quads
        if (idx < 262144) {                // W_skip: 1024x1024 -> Bc (coff 0)
            int r = idx >> 8, c4 = (idx & 255) << 2;
            pack4(*(const float4*)(Wsk + (size_t)r * 1024 + c4), Bc + (size_t)r * KTOT + c4);
        } else {                           // W_mix: 1024x2048 -> Bc (coff 1024)
            int i = idx - 262144;
            int r = i >> 9, c4 = (i & 511) << 2;
            pack4(*(const float4*)(Wmx + (size_t)r * 2048 + c4), Bc + (size_t)r * KTOT + 1024 + c4);
        }
        return;
    }
    if (threadIdx.x >= 64) return;
    const int pair = blockIdx.x * 64 + threadIdx.x;  // 16*64 = 1024
    const int m = pair >> 4, c = pair & 15;
    float am = a[m], th = bfreq[c];
    float e = expf(-64.f * fabsf(am));
    float sn, cs; sincosf(64.f * th, &sn, &cs);
    float gr = e * cs, gi = e * sn;
    float cre = state_re[pair], cim = state_im[pair];

    float2 pf[8]; int rsv[8];
#pragma unroll
    for (int j = 0; j < 8; ++j) { pf[j] = local_end[(size_t)j * 1024 + pair]; rsv[j] = reset_any[j]; }
    for (int kb = 0; kb < NCHUNK; kb += 8) {
        float2 cur[8]; int rs[8];
#pragma unroll
        for (int j = 0; j < 8; ++j) { cur[j] = pf[j]; rs[j] = rsv[j]; }
        if (kb + 8 < NCHUNK) {
#pragma unroll
            for (int j = 0; j < 8; ++j) {
                pf[j]  = local_end[(size_t)(kb + 8 + j) * 1024 + pair];
                rsv[j] = reset_any[kb + 8 + j];
            }
        }
#pragma unroll
        for (int j = 0; j < 8; ++j) {
            carry_in[(size_t)(kb + j) * 1024 + pair] = make_float2(cre, cim);
            if (rs[j]) { cre = cur[j].x; cim = cur[j].y; }
            else {
                float t = gr * cre - gi * cim + cur[j].x;
                cim = gr * cim + gi * cre + cur[j].y;
                cre = t;
            }
        }
    }
    if (pair < tail_n)        out_tail[pair]        = cre;
    if (1024 + pair < tail_n) out_tail[1024 + pair] = cim;
}

// ---------------- scan phase 3: 256 blocks — chunk k = b>>1, pair-half h = b&1 ----------------
__global__ void scan_phase3(const float* __restrict__ pre_raw, const int* __restrict__ start,
                            const float* __restrict__ a, const float* __restrict__ bfreq,
                            const float2* __restrict__ carry_in, bf16* __restrict__ A) {
    __shared__ float pn[CH][TRACE + 1];
    __shared__ float rn[CH];
    __shared__ int sf[CH];
    const int k = blockIdx.x >> 1, h = blockIdx.x & 1, tid = threadIdx.x;
    for (int idx = tid; idx < CH * TRACE; idx += 256) {
        int r = idx >> 6, m = idx & 63;
        pn[r][m] = pre_raw[(size_t)(k * CH + r) * TRACE + m];
    }
    if (tid < CH) sf[tid] = start[k * CH + tid];
    __syncthreads();
    if (tid < CH) {
        float s = 0.f;
#pragma unroll
        for (int m = 0; m < TRACE; ++m) { float v = pn[tid][m]; s += v * v; }
        rn[tid] = 1.0f / (1e-6f + sqrtf(s));
    }
    __syncthreads();
    {
        int p0 = h * 512 + tid * 2;           // this block covers pairs [h*512, h*512+512)
        int m = p0 >> 4, c0 = p0 & 15;
        float am = a[m];
        float e = expf(-fabsf(am));
        float sn0, cs0, sn1, cs1;
        sincosf(bfreq[c0], &sn0, &cs0);
        sincosf(bfreq[c0 + 1], &sn1, &cs1);
        float gr0 = e * cs0, gi0 = e * sn0;
        float gr1 = e * cs1, gi1 = e * sn1;
        float4 ci = *(const float4*)&carry_in[(size_t)k * 1024 + p0];
        float sre0 = ci.x, sim0 = ci.y, sre1 = ci.z, sim1 = ci.w;
        for (int r = 0; r < CH; ++r) {
            float p = pn[r][m] * rn[r];
            if (sf[r]) { sre0 = p; sim0 = 0.f; sre1 = p; sim1 = 0.f; }
            else {
                float t0 = gr0 * sre0 - gi0 * sim0 + p; sim0 = gr0 * sim0 + gi0 * sre0; sre0 = t0;
                float t1 = gr1 * sre1 - gi1 * sim1 + p; sim1 = gr1 * sim1 + gi1 * sre1; sre1 = t1;
            }
            size_t off = (size_t)(k * CH + r) * KTOT + 1024 + m * 32;
            union { bf16 h2[2]; uint32_t u; } pr, pi;
            pr.h2[0] = __float2bfloat16(sre0); pr.h2[1] = __float2bfloat16(sre1);
            pi.h2[0] = __float2bfloat16(sim0); pi.h2[1] = __float2bfloat16(sim1);
            *(uint32_t*)(A + off + c0)      = pr.u;
            *(uint32_t*)(A + off + 16 + c0) = pi.u;
        }
    }
}

// ---------------- main GEMM: 128x128 tile, BK=32, grid 512 = 2 blocks/CU ----------------
// 4 waves (2Mx2N, 64x64/wave), 3 LDS buffers (48 KB), stage-ahead-2, counted vmcnt(4).
// Per K-tile: { 8 ds_read_b128 ; stage tile u+2 (4 gload_lds) ; BAR ; setprio 16 MFMA ;
//               vmcnt(4|0) ; lgkmcnt(0) ; BAR }.
// Swizzle (64B rows): unit' = unit ^ ((row>>1)&3) -> fragment read = 2-way (free);
// staging pre-swizzles the GLOBAL source with the same involution (rule #21).
// XCD map: xcd owns 8 contiguous row-panels x all 8 col-tiles (FETCH stays compulsory).
__global__ __launch_bounds__(256) void gemm_main(const bf16* __restrict__ A,  // [8192][3072]
                                                 const bf16* __restrict__ B,  // [1024][3072]
                                                 const float* __restrict__ bskip,
                                                 const float* __restrict__ bmix,
                                                 float* __restrict__ out) {   // [8192][1024]
    __shared__ short As[3][128 * 32];   // 24 KB
    __shared__ short Bs[3][128 * 32];   // 24 KB
    const int tid = threadIdx.x;
    const int lane = tid & 63, wv = tid >> 6;        // 4 waves
    const int wm = wv >> 1, wn = wv & 1;
    const int wg = blockIdx.x;
    const int xcd = wg & 7, bidx = wg >> 3;          // 64 blocks per XCD
    const int row0 = (xcd * 8 + (bidx >> 3)) * 128;  // 64 row tiles
    const int col0 = (bidx & 7) * 128;               // 8 col tiles

    // staging source swizzle: lane covers row base16+(lane>>2), physical unit lane&3;
    // loads global k-unit (lane&3) ^ ((row>>1)&3) = (lane&3) ^ ((lane>>3)&3).
    const int kswst = ((lane & 3) ^ ((lane >> 3) & 3)) << 3;   // shorts

    auto stageK = [&](int su, int bd) {
#pragma unroll
        for (int j = 0; j < 2; ++j) {
            int chunk = wv * 2 + j;                  // 16-row chunk 0..7
            int r = chunk * 16 + (lane >> 2);
            const bf16* ga = A + (size_t)(row0 + r) * KTOT + su * 32 + kswst;
            __builtin_amdgcn_global_load_lds((const AS1 void*)ga,
                (AS3 void*)&As[bd][chunk * 512], 16, 0, 0);
            const bf16* gb = B + (size_t)(col0 + r) * KTOT + su * 32 + kswst;
            __builtin_amdgcn_global_load_lds((const AS1 void*)gb,
                (AS3 void*)&Bs[bd][chunk * 512], 16, 0, 0);
        }
    };

    f32x4 acc[4][4];
#pragma unroll
    for (int i = 0; i < 4; ++i)
#pragma unroll
        for (int j = 0; j < 4; ++j) acc[i][j] = (f32x4)0.0f;

    const int lr = lane & 15, hi = lane >> 4;
    // read swizzle: logical unit hi at row R -> physical hi ^ ((R>>1)&3); (R>>1)&3 = (lr>>1)&3.
    const int sw = ((hi ^ ((lr >> 1) & 3)) << 3);    // shorts

    auto kphase = [&](int bc, int su, int bd, int vm) {
        s16x8 af[4], bfr[4];
#pragma unroll
        for (int i = 0; i < 4; ++i)
            af[i] = *(const s16x8*)&As[bc][(wm * 64 + i * 16 + lr) * 32 + sw];
#pragma unroll
        for (int j = 0; j < 4; ++j)
            bfr[j] = *(const s16x8*)&Bs[bc][(wn * 64 + j * 16 + lr) * 32 + sw];
        if (su < 96) stageK(su, bd);
        BAR();
        __builtin_amdgcn_s_setprio(1);
#pragma unroll
        for (int i = 0; i < 4; ++i)
#pragma unroll
            for (int j = 0; j < 4; ++j)
                acc[i][j] = __builtin_amdgcn_mfma_f32_16x16x32_bf16(af[i], bfr[j], acc[i][j], 0, 0, 0);
        __builtin_amdgcn_s_setprio(0);
        if (vm == 4) asm volatile("s_waitcnt vmcnt(4)" ::: "memory");
        else         asm volatile("s_waitcnt vmcnt(0)" ::: "memory");
        asm volatile("s_waitcnt lgkmcnt(0)" ::: "memory");  // free: reads consumed; closes WAR
        BAR();
    };

    // prologue: stage tiles 0,1; vmcnt(4) -> tile 0 landed; publish.
    stageK(0, 0); stageK(1, 1);
    asm volatile("s_waitcnt vmcnt(4)" ::: "memory");
    BAR();

    // steady state: u consumes buf u%3, stages tile u+2 into buf (u+2)%3.
    // vmcnt(4) leaves tile u+2's 4 loads in flight; tile u+1 landed. Drain at u>=94.
    for (int t = 0; t < 32; ++t) {
        int u0 = 3 * t;
        kphase(0, u0 + 2, 2, (u0     < 94) ? 4 : 0);
        kphase(1, u0 + 3, 0, (u0 + 1 < 94) ? 4 : 0);
        kphase(2, u0 + 4, 1, (u0 + 2 < 94) ? 4 : 0);
    }

    const int lg = lane >> 4;
#pragma unroll
    for (int j = 0; j < 4; ++j) {
        int col = col0 + wn * 64 + j * 16 + lr;
        float bias = bskip[col] + bmix[col];
#pragma unroll
        for (int i = 0; i < 4; ++i) {
            int rbase = row0 + wm * 64 + i * 16 + lg * 4;
#pragma unroll
            for (int r = 0; r < 4; ++r)
                out[(size_t)(rbase + r) * DOUT + col] = acc[i][j][r] + bias;
        }
    }
}

extern "C" void kernel_launch(void* const* d_in, const int* in_sizes, int n_in,
                              void* d_out, int out_size, void* d_ws, size_t ws_size,
                              hipStream_t stream) {
    const float* x        = (const float*)d_in[0];
    const float* state_re = (const float*)d_in[1];
    const float* state_im = (const float*)d_in[2];
    const int*   start    = (const int*)d_in[3];
    const float* W_pre    = (const float*)d_in[5];
    const float* b_pre    = (const float*)d_in[6];
    const float* W_skip   = (const float*)d_in[7];
    const float* b_skip   = (const float*)d_in[8];
    const float* W_mix    = (const float*)d_in[9];
    const float* b_mix    = (const float*)d_in[10];
    const float* a_dec    = (const float*)d_in[11];
    const float* b_freq   = (const float*)d_in[12];

    uint8_t* ws = (uint8_t*)d_ws;
    bf16*  A         = (bf16*)(ws);                 // 50331648
    bf16*  Bc        = (bf16*)(ws + 50331648);      // 6291456
    bf16*  Wp        = (bf16*)(ws + 56623104);      // 131072
    float* pre_raw   = (float*)(ws + 56754176);     // 2097152
    float2* local_end= (float2*)(ws + 58851328);    // 1048576
    float2* carry_in = (float2*)(ws + 59899904);    // 1048576
    int*   reset_any = (int*)(ws + 60948480);       // 512

    cvt_x<<<dim3((2113536 + 255) / 256), 256, 0, stream>>>(x, W_pre, A, Wp);

    pre_scan1<<<dim3(NCHUNK), 256, 0, stream>>>(A, Wp, b_pre, start, a_dec, b_freq,
                                                pre_raw, local_end, reset_any);
    int tail_n = out_size - 8192 * 1024;
    if (tail_n < 0) tail_n = 0;
    if (tail_n > 2048) tail_n = 2048;
    scan_phase2w<<<dim3(16 + 3072), 256, 0, stream>>>(local_end, reset_any, state_re, state_im,
                                                      a_dec, b_freq, carry_in,
                                                      (float*)d_out + 8192 * 1024, tail_n,
                                                      W_skip, W_mix, Bc);
    scan_phase3<<<dim3(2 * NCHUNK), 256, 0, stream>>>(pre_raw, start, a_dec, b_freq, carry_in, A);

    gemm_main<<<dim3(512), 256, 0, stream>>>(A, Bc, b_skip, b_mix, (float*)d_out);
}

// Round 19
// 119.344 us; speedup vs baseline: 1.0379x; 1.0004x over previous
//
#include <hip/hip_runtime.h>
#include <hip/hip_bf16.h>
#include <stdint.h>

#define T_LEN 8192
#define DIN   1024
#define DOUT  1024
#define TRACE 64
#define CTX   16
#define KTOT  3072      // DIN + 2*TRACE*CTX
#define CH    64        // scan chunk length
#define NCHUNK 128      // T_LEN / CH

#define AS1 __attribute__((address_space(1)))
#define AS3 __attribute__((address_space(3)))

// Compile-time-fenced barrier (r9 race fix: intrinsic barrier is not a compiler fence).
#define BAR() asm volatile("s_barrier" ::: "memory")

using bf16 = __hip_bfloat16;
typedef __attribute__((ext_vector_type(4))) float f32x4;
typedef __attribute__((ext_vector_type(8))) short s16x8;

__device__ __forceinline__ void pack4(const float4 v, void* dst) {
    union { bf16 h[4]; uint2 u; } pk;
    pk.h[0] = __float2bfloat16(v.x); pk.h[1] = __float2bfloat16(v.y);
    pk.h[2] = __float2bfloat16(v.z); pk.h[3] = __float2bfloat16(v.w);
    *(uint2*)dst = pk.u;
}

// ---------------- f32 -> bf16: x and W_pre only (weights ride phase2w) ----------------
__global__ void cvt_x(const float* __restrict__ x, const float* __restrict__ Wpre,
                      bf16* __restrict__ A, bf16* __restrict__ Wp) {
    int idx = blockIdx.x * 256 + threadIdx.x;
    if (idx < 2097152) {                       // x: 8192x1024 -> A (ld 3072)
        int r = idx >> 8, c4 = (idx & 255) << 2;
        pack4(*(const float4*)(x + (size_t)r * 1024 + c4), A + (size_t)r * KTOT + c4);
    } else if (idx < 2113536) {                // W_pre: 64x1024 -> Wp (ld 1024)
        int i = idx - 2097152;
        int r = i >> 8, c4 = (i & 255) << 2;
        pack4(*(const float4*)(Wpre + (size_t)r * 1024 + c4), Wp + (size_t)r * 1024 + c4);
    }
}

// ---------------- fused pre-GEMM + scan phase 1 (r10/r15 version) ----------------
__global__ __launch_bounds__(256) void pre_scan1(
    const bf16* __restrict__ A,     // [8192][KTOT], x part (k<1024)
    const bf16* __restrict__ Wp,    // [64][1024]
    const float* __restrict__ bpre,
    const int* __restrict__ start,
    const float* __restrict__ a, const float* __restrict__ bfreq,
    float* __restrict__ pre_raw,    // [8192][64]
    float2* __restrict__ local_end, // [128][1024]
    int* __restrict__ reset_any) {  // [128]
    __shared__ short As[2][64 * 32];
    __shared__ short Bs[2][64 * 32];
    __shared__ float pn[CH][TRACE + 1];
    __shared__ float rn[CH];
    __shared__ int sf[CH];
    const int tid = threadIdx.x, lane = tid & 63, wv = tid >> 6;
    const int row0 = blockIdx.x * 64;
    const int l4 = lane >> 2, c8 = (lane & 3) * 8;

    auto stage = [&](int kt, int buf) {
        int r = wv * 16 + l4;
        const bf16* ga = A + (size_t)(row0 + r) * KTOT + kt * 32 + c8;
        const bf16* gb = Wp + (size_t)r * 1024 + kt * 32 + c8;
        __builtin_amdgcn_global_load_lds(
            (const AS1 void*)ga, (AS3 void*)&As[buf][wv * 512], 16, 0, 0);
        __builtin_amdgcn_global_load_lds(
            (const AS1 void*)gb, (AS3 void*)&Bs[buf][wv * 512], 16, 0, 0);
    };

    f32x4 acc[4];
#pragma unroll
    for (int j = 0; j < 4; ++j) acc[j] = (f32x4)0.0f;

    stage(0, 0);
    __syncthreads();
    int buf = 0;
    const int lr = lane & 15, lk = (lane >> 4) * 8;
    for (int kt = 0; kt < 32; ++kt) {
        if (kt + 1 < 32) stage(kt + 1, buf ^ 1);
        s16x8 af = *(const s16x8*)&As[buf][(wv * 16 + lr) * 32 + lk];
        s16x8 bfr[4];
#pragma unroll
        for (int j = 0; j < 4; ++j)
            bfr[j] = *(const s16x8*)&Bs[buf][(j * 16 + lr) * 32 + lk];
#pragma unroll
        for (int j = 0; j < 4; ++j)
            acc[j] = __builtin_amdgcn_mfma_f32_16x16x32_bf16(af, bfr[j], acc[j], 0, 0, 0);
        __syncthreads();
        buf ^= 1;
    }
    const int lg = lane >> 4;
#pragma unroll
    for (int j = 0; j < 4; ++j) {
        int col = j * 16 + lr;
        float bias = bpre[col];
#pragma unroll
        for (int r = 0; r < 4; ++r) {
            int rl = wv * 16 + lg * 4 + r;
            float v = acc[j][r] + bias;
            pn[rl][col] = v;
            pre_raw[(size_t)(row0 + rl) * TRACE + col] = v;
        }
    }
    if (tid < CH) sf[tid] = start[row0 + tid];
    __syncthreads();
    if (tid < CH) {
        float s = 0.f;
#pragma unroll
        for (int m = 0; m < TRACE; ++m) { float v = pn[tid][m]; s += v * v; }
        rn[tid] = 1.0f / (1e-6f + sqrtf(s));
        int any = __any(sf[tid] != 0);
        if (tid == 0) reset_any[blockIdx.x] = any;
    }
    __syncthreads();
#pragma unroll
    for (int q = 0; q < 4; ++q) {
        int pair = tid + q * 256;
        int m = pair >> 4, c = pair & 15;
        float am = a[m], th = bfreq[c];
        float e = expf(-fabsf(am));
        float sn, cs; sincosf(th, &sn, &cs);
        float gr = e * cs, gi = e * sn;
        float sre = 0.f, sim = 0.f;
        for (int r = 0; r < CH; ++r) {
            float p = pn[r][m] * rn[r];
            if (sf[r]) { sre = p; sim = 0.f; }
            else { float t = gr * sre - gi * sim + p; sim = gr * sim + gi * sre; sre = t; }
        }
        local_end[(size_t)blockIdx.x * 1024 + pair] = make_float2(sre, sim);
    }
}

// ---------------- scan phase 2 (blocks 0-15) + weight cvt (blocks 16+) ----------------
__global__ void scan_phase2w(const float2* __restrict__ local_end, const int* __restrict__ reset_any,
                             const float* __restrict__ state_re, const float* __restrict__ state_im,
                             const float* __restrict__ a, const float* __restrict__ bfreq,
                             float2* __restrict__ carry_in, float* __restrict__ out_tail, int tail_n,
                             const float* __restrict__ Wsk, const float* __restrict__ Wmx,
                             bf16* __restrict__ Bc) {
    if (blockIdx.x >= 16) {
        int idx = (blockIdx.x - 16) * 256 + threadIdx.x;  // 786432 quads
        if (idx < 262144) {                // W_skip: 1024x1024 -> Bc (coff 0)
            int r = idx >> 8, c4 = (idx & 255) << 2;
            pack4(*(const float4*)(Wsk + (size_t)r * 1024 + c4), Bc + (size_t)r * KTOT + c4);
        } else {                           // W_mix: 1024x2048 -> Bc (coff 1024)
            int i = idx - 262144;
            int r = i >> 9, c4 = (i & 511) << 2;
            pack4(*(const float4*)(Wmx + (size_t)r * 2048 + c4), Bc + (size_t)r * KTOT + 1024 + c4);
        }
        return;
    }
    if (threadIdx.x >= 64) return;
    const int pair = blockIdx.x * 64 + threadIdx.x;  // 16*64 = 1024
    const int m = pair >> 4, c = pair & 15;
    float am = a[m], th = bfreq[c];
    float e = expf(-64.f * fabsf(am));
    float sn, cs; sincosf(64.f * th, &sn, &cs);
    float gr = e * cs, gi = e * sn;
    float cre = state_re[pair], cim = state_im[pair];

    float2 pf[8]; int rsv[8];
#pragma unroll
    for (int j = 0; j < 8; ++j) { pf[j] = local_end[(size_t)j * 1024 + pair]; rsv[j] = reset_any[j]; }
    for (int kb = 0; kb < NCHUNK; kb += 8) {
        float2 cur[8]; int rs[8];
#pragma unroll
        for (int j = 0; j < 8; ++j) { cur[j] = pf[j]; rs[j] = rsv[j]; }
        if (kb + 8 < NCHUNK) {
#pragma unroll
            for (int j = 0; j < 8; ++j) {
                pf[j]  = local_end[(size_t)(kb + 8 + j) * 1024 + pair];
                rsv[j] = reset_any[kb + 8 + j];
            }
        }
#pragma unroll
        for (int j = 0; j < 8; ++j) {
            carry_in[(size_t)(kb + j) * 1024 + pair] = make_float2(cre, cim);
            if (rs[j]) { cre = cur[j].x; cim = cur[j].y; }
            else {
                float t = gr * cre - gi * cim + cur[j].x;
                cim = gr * cim + gi * cre + cur[j].y;
                cre = t;
            }
        }
    }
    if (pair < tail_n)        out_tail[pair]        = cre;
    if (1024 + pair < tail_n) out_tail[1024 + pair] = cim;
}

// ---------------- scan phase 3: 256 blocks — chunk k = b>>1, pair-half h = b&1 ----------------
__global__ void scan_phase3(const float* __restrict__ pre_raw, const int* __restrict__ start,
                            const float* __restrict__ a, const float* __restrict__ bfreq,
                            const float2* __restrict__ carry_in, bf16* __restrict__ A) {
    __shared__ float pn[CH][TRACE + 1];
    __shared__ float rn[CH];
    __shared__ int sf[CH];
    const int k = blockIdx.x >> 1, h = blockIdx.x & 1, tid = threadIdx.x;
    for (int idx = tid; idx < CH * TRACE; idx += 256) {
        int r = idx >> 6, m = idx & 63;
        pn[r][m] = pre_raw[(size_t)(k * CH + r) * TRACE + m];
    }
    if (tid < CH) sf[tid] = start[k * CH + tid];
    __syncthreads();
    if (tid < CH) {
        float s = 0.f;
#pragma unroll
        for (int m = 0; m < TRACE; ++m) { float v = pn[tid][m]; s += v * v; }
        rn[tid] = 1.0f / (1e-6f + sqrtf(s));
    }
    __syncthreads();
    {
        int p0 = h * 512 + tid * 2;           // this block covers pairs [h*512, h*512+512)
        int m = p0 >> 4, c0 = p0 & 15;
        float am = a[m];
        float e = expf(-fabsf(am));
        float sn0, cs0, sn1, cs1;
        sincosf(bfreq[c0], &sn0, &cs0);
        sincosf(bfreq[c0 + 1], &sn1, &cs1);
        float gr0 = e * cs0, gi0 = e * sn0;
        float gr1 = e * cs1, gi1 = e * sn1;
        float4 ci = *(const float4*)&carry_in[(size_t)k * 1024 + p0];
        float sre0 = ci.x, sim0 = ci.y, sre1 = ci.z, sim1 = ci.w;
        for (int r = 0; r < CH; ++r) {
            float p = pn[r][m] * rn[r];
            if (sf[r]) { sre0 = p; sim0 = 0.f; sre1 = p; sim1 = 0.f; }
            else {
                float t0 = gr0 * sre0 - gi0 * sim0 + p; sim0 = gr0 * sim0 + gi0 * sre0; sre0 = t0;
                float t1 = gr1 * sre1 - gi1 * sim1 + p; sim1 = gr1 * sim1 + gi1 * sre1; sre1 = t1;
            }
            size_t off = (size_t)(k * CH + r) * KTOT + 1024 + m * 32;
            union { bf16 h2[2]; uint32_t u; } pr, pi;
            pr.h2[0] = __float2bfloat16(sre0); pr.h2[1] = __float2bfloat16(sre1);
            pi.h2[0] = __float2bfloat16(sim0); pi.h2[1] = __float2bfloat16(sim1);
            *(uint32_t*)(A + off + c0)      = pr.u;
            *(uint32_t*)(A + off + 16 + c0) = pi.u;
        }
    }
}

// ---------------- main GEMM: 128x128 tile, BK=32, 8 waves, 2 blocks/CU ----------------
// 512 thr (8 waves 2Mx4N, wave tile 64x32), grid 512 = 256 CUs x 2 blocks (49 KB LDS).
// 16 waves/CU -> cross-block overlap fills barrier/wait stalls (m114 mechanism).
// Per K-tile: { 6 ds_read_b128 ; stage tile u+2 (2 gload_lds) ; BAR ;
//               setprio 8 MFMA ; vmcnt(2|0) ; lgkmcnt(0) ; BAR }, 3-buffer rotation.
// r18 bugfix: LDS stage base is wv*512 SHORTS (16 rows x 64 B = 1024 B), was wv*1024.
__global__ __launch_bounds__(512) void gemm_main(const bf16* __restrict__ A,  // [8192][3072]
                                                 const bf16* __restrict__ B,  // [1024][3072]
                                                 const float* __restrict__ bskip,
                                                 const float* __restrict__ bmix,
                                                 float* __restrict__ out) {   // [8192][1024]
    __shared__ short As[3][128 * 32];   // 24 KB
    __shared__ short Bs[3][128 * 32];   // 24 KB
    const int tid = threadIdx.x;
    const int lane = tid & 63, wv = tid >> 6;        // 8 waves
    const int wm = wv >> 2, wn = wv & 3;             // 2M x 4N, wave tile 64x32
    const int wg = blockIdx.x;
    const int xcd = wg & 7, bidx = wg >> 3;          // 64 blocks per XCD (all co-resident)
    const int row0 = (xcd * 8 + (bidx >> 3)) * 128;  // 64 row tiles
    const int col0 = (bidx & 7) * 128;               // 8 col tiles

    // staging: thread covers row r = wv*16 + (lane>>2), 16B unit lane&3, pre-swizzled.
    // (r>>1)&3 == (lane>>3)&3 because wv*8 % 4 == 0.
    const int kswst = ((lane & 3) ^ ((lane >> 3) & 3)) << 3;   // shorts

    auto stageK = [&](int su, int bd) {
        int r = wv * 16 + (lane >> 2);
        const bf16* ga = A + (size_t)(row0 + r) * KTOT + su * 32 + kswst;
        __builtin_amdgcn_global_load_lds((const AS1 void*)ga,
            (AS3 void*)&As[bd][wv * 512], 16, 0, 0);
        const bf16* gb = B + (size_t)(col0 + r) * KTOT + su * 32 + kswst;
        __builtin_amdgcn_global_load_lds((const AS1 void*)gb,
            (AS3 void*)&Bs[bd][wv * 512], 16, 0, 0);
    };

    f32x4 acc[4][2];
#pragma unroll
    for (int i = 0; i < 4; ++i)
#pragma unroll
        for (int j = 0; j < 2; ++j) acc[i][j] = (f32x4)0.0f;

    const int lr = lane & 15, hi = lane >> 4;
    const int sw = ((hi ^ ((lr >> 1) & 3)) << 3);    // read swizzle (shorts)

    auto kphase = [&](int bc, int su, int bd, int vm) {
        s16x8 af[4], bfr[2];
#pragma unroll
        for (int i = 0; i < 4; ++i)
            af[i] = *(const s16x8*)&As[bc][(wm * 64 + i * 16 + lr) * 32 + sw];
#pragma unroll
        for (int j = 0; j < 2; ++j)
            bfr[j] = *(const s16x8*)&Bs[bc][(wn * 32 + j * 16 + lr) * 32 + sw];
        if (su < 96) stageK(su, bd);
        BAR();
        __builtin_amdgcn_s_setprio(1);
#pragma unroll
        for (int i = 0; i < 4; ++i)
#pragma unroll
            for (int j = 0; j < 2; ++j)
                acc[i][j] = __builtin_amdgcn_mfma_f32_16x16x32_bf16(af[i], bfr[j], acc[i][j], 0, 0, 0);
        __builtin_amdgcn_s_setprio(0);
        if (vm == 2) asm volatile("s_waitcnt vmcnt(2)" ::: "memory");
        else         asm volatile("s_waitcnt vmcnt(0)" ::: "memory");
        asm volatile("s_waitcnt lgkmcnt(0)" ::: "memory");  // free: reads consumed; closes WAR
        BAR();
    };

    // prologue: stage tiles 0,1; vmcnt(2) -> tile 0 landed; publish.
    stageK(0, 0); stageK(1, 1);
    asm volatile("s_waitcnt vmcnt(2)" ::: "memory");
    BAR();

    // steady state: tile u consumes buf u%3, stages u+2 into (u+2)%3.
    // vmcnt(2) leaves u+2's 2 loads in flight; u+1 landed. Drain at u>=94.
    for (int t = 0; t < 32; ++t) {
        int u0 = 3 * t;
        kphase(0, u0 + 2, 2, (u0     < 94) ? 2 : 0);
        kphase(1, u0 + 3, 0, (u0 + 1 < 94) ? 2 : 0);
        kphase(2, u0 + 4, 1, (u0 + 2 < 94) ? 2 : 0);
    }

    const int lg = lane >> 4;
#pragma unroll
    for (int j = 0; j < 2; ++j) {
        int col = col0 + wn * 32 + j * 16 + lr;
        float bias = bskip[col] + bmix[col];
#pragma unroll
        for (int i = 0; i < 4; ++i) {
            int rbase = row0 + wm * 64 + i * 16 + lg * 4;
#pragma unroll
            for (int r = 0; r < 4; ++r)
                out[(size_t)(rbase + r) * DOUT + col] = acc[i][j][r] + bias;
        }
    }
}

extern "C" void kernel_launch(void* const* d_in, const int* in_sizes, int n_in,
                              void* d_out, int out_size, void* d_ws, size_t ws_size,
                              hipStream_t stream) {
    const float* x        = (const float*)d_in[0];
    const float* state_re = (const float*)d_in[1];
    const float* state_im = (const float*)d_in[2];
    const int*   start    = (const int*)d_in[3];
    const float* W_pre    = (const float*)d_in[5];
    const float* b_pre    = (const float*)d_in[6];
    const float* W_skip   = (const float*)d_in[7];
    const float* b_skip   = (const float*)d_in[8];
    const float* W_mix    = (const float*)d_in[9];
    const float* b_mix    = (const float*)d_in[10];
    const float* a_dec    = (const float*)d_in[11];
    const float* b_freq   = (const float*)d_in[12];

    uint8_t* ws = (uint8_t*)d_ws;
    bf16*  A         = (bf16*)(ws);                 // 50331648
    bf16*  Bc        = (bf16*)(ws + 50331648);      // 6291456
    bf16*  Wp        = (bf16*)(ws + 56623104);      // 131072
    float* pre_raw   = (float*)(ws + 56754176);     // 2097152
    float2* local_end= (float2*)(ws + 58851328);    // 1048576
    float2* carry_in = (float2*)(ws + 59899904);    // 1048576
    int*   reset_any = (int*)(ws + 60948480);       // 512

    cvt_x<<<dim3((2113536 + 255) / 256), 256, 0, stream>>>(x, W_pre, A, Wp);

    pre_scan1<<<dim3(NCHUNK), 256, 0, stream>>>(A, Wp, b_pre, start, a_dec, b_freq,
                                                pre_raw, local_end, reset_any);
    int tail_n = out_size - 8192 * 1024;
    if (tail_n < 0) tail_n = 0;
    if (tail_n > 2048) tail_n = 2048;
    scan_phase2w<<<dim3(16 + 3072), 256, 0, stream>>>(local_end, reset_any, state_re, state_im,
                                                      a_dec, b_freq, carry_in,
                                                      (float*)d_out + 8192 * 1024, tail_n,
                                                      W_skip, W_mix, Bc);
    scan_phase3<<<dim3(2 * NCHUNK), 256, 0, stream>>>(pre_raw, start, a_dec, b_freq, carry_in, A);

    gemm_main<<<dim3(512), 512, 0, stream>>>(A, Bc, b_skip, b_mix, (float*)d_out);
}

// Round 20
// 112.254 us; speedup vs baseline: 1.1034x; 1.0632x over previous
//
#include <hip/hip_runtime.h>
#include <hip/hip_bf16.h>
#include <stdint.h>

#define T_LEN 8192
#define DIN   1024
#define DOUT  1024
#define TRACE 64
#define CTX   16
#define KTOT  3072      // DIN + 2*TRACE*CTX
#define CH    64        // scan chunk length
#define NCHUNK 128      // T_LEN / CH

#define AS1 __attribute__((address_space(1)))
#define AS3 __attribute__((address_space(3)))

// Compile-time-fenced barrier (r9 race fix: intrinsic barrier is not a compiler fence).
#define BAR() asm volatile("s_barrier" ::: "memory")

using bf16 = __hip_bfloat16;
typedef __attribute__((ext_vector_type(4))) float f32x4;
typedef __attribute__((ext_vector_type(8))) short s16x8;

__device__ __forceinline__ void pack4(const float4 v, void* dst) {
    union { bf16 h[4]; uint2 u; } pk;
    pk.h[0] = __float2bfloat16(v.x); pk.h[1] = __float2bfloat16(v.y);
    pk.h[2] = __float2bfloat16(v.z); pk.h[3] = __float2bfloat16(v.w);
    *(uint2*)dst = pk.u;
}

// ---------------- f32 -> bf16: x and W_pre only (weights ride phase2w) ----------------
__global__ void cvt_x(const float* __restrict__ x, const float* __restrict__ Wpre,
                      bf16* __restrict__ A, bf16* __restrict__ Wp) {
    int idx = blockIdx.x * 256 + threadIdx.x;
    if (idx < 2097152) {                       // x: 8192x1024 -> A (ld 3072)
        int r = idx >> 8, c4 = (idx & 255) << 2;
        pack4(*(const float4*)(x + (size_t)r * 1024 + c4), A + (size_t)r * KTOT + c4);
    } else if (idx < 2113536) {                // W_pre: 64x1024 -> Wp (ld 1024)
        int i = idx - 2097152;
        int r = i >> 8, c4 = (i & 255) << 2;
        pack4(*(const float4*)(Wpre + (size_t)r * 1024 + c4), Wp + (size_t)r * 1024 + c4);
    }
}

// ---------------- fused pre-GEMM + scan phase 1 — 512 threads (8 waves) ----------------
// Wave w: rows (w&3)*16.. , cols (w>>2)*32.. (2 MFMA/K-step).
// Staging: waves 0-3 load A slice (w&3), waves 4-7 load Wp slice (w-4).
__global__ __launch_bounds__(512) void pre_scan1(
    const bf16* __restrict__ A,     // [8192][KTOT], x part (k<1024)
    const bf16* __restrict__ Wp,    // [64][1024]
    const float* __restrict__ bpre,
    const int* __restrict__ start,
    const float* __restrict__ a, const float* __restrict__ bfreq,
    float* __restrict__ pre_raw,    // [8192][64]
    float2* __restrict__ local_end, // [128][1024]
    int* __restrict__ reset_any) {  // [128]
    __shared__ short As[2][64 * 32];
    __shared__ short Bs[2][64 * 32];
    __shared__ float pn[CH][TRACE + 1];
    __shared__ float rn[CH];
    __shared__ int sf[CH];
    const int tid = threadIdx.x, lane = tid & 63, wv = tid >> 6;   // 8 waves
    const int row0 = blockIdx.x * 64;
    const int l4 = lane >> 2, c8 = (lane & 3) * 8;
    const int wm = wv & 3, wn = wv >> 2;

    auto stage = [&](int kt, int buf) {
        if (wv < 4) {
            int r = wv * 16 + l4;
            const bf16* ga = A + (size_t)(row0 + r) * KTOT + kt * 32 + c8;
            __builtin_amdgcn_global_load_lds(
                (const AS1 void*)ga, (AS3 void*)&As[buf][wv * 512], 16, 0, 0);
        } else {
            int r = (wv - 4) * 16 + l4;
            const bf16* gb = Wp + (size_t)r * 1024 + kt * 32 + c8;
            __builtin_amdgcn_global_load_lds(
                (const AS1 void*)gb, (AS3 void*)&Bs[buf][(wv - 4) * 512], 16, 0, 0);
        }
    };

    f32x4 acc[2];
#pragma unroll
    for (int j = 0; j < 2; ++j) acc[j] = (f32x4)0.0f;

    stage(0, 0);
    __syncthreads();
    int buf = 0;
    const int lr = lane & 15, lk = (lane >> 4) * 8;
    for (int kt = 0; kt < 32; ++kt) {
        if (kt + 1 < 32) stage(kt + 1, buf ^ 1);
        s16x8 af = *(const s16x8*)&As[buf][(wm * 16 + lr) * 32 + lk];
        s16x8 bfr[2];
#pragma unroll
        for (int j = 0; j < 2; ++j)
            bfr[j] = *(const s16x8*)&Bs[buf][(wn * 32 + j * 16 + lr) * 32 + lk];
#pragma unroll
        for (int j = 0; j < 2; ++j)
            acc[j] = __builtin_amdgcn_mfma_f32_16x16x32_bf16(af, bfr[j], acc[j], 0, 0, 0);
        __syncthreads();
        buf ^= 1;
    }
    const int lg = lane >> 4;
#pragma unroll
    for (int j = 0; j < 2; ++j) {
        int col = wn * 32 + j * 16 + lr;
        float bias = bpre[col];
#pragma unroll
        for (int r = 0; r < 4; ++r) {
            int rl = wm * 16 + lg * 4 + r;
            float v = acc[j][r] + bias;
            pn[rl][col] = v;
            pre_raw[(size_t)(row0 + rl) * TRACE + col] = v;
        }
    }
    if (tid < CH) sf[tid] = start[row0 + tid];
    __syncthreads();
    if (tid < CH) {
        float s = 0.f;
#pragma unroll
        for (int m = 0; m < TRACE; ++m) { float v = pn[tid][m]; s += v * v; }
        rn[tid] = 1.0f / (1e-6f + sqrtf(s));
        int any = __any(sf[tid] != 0);
        if (tid == 0) reset_any[blockIdx.x] = any;
    }
    __syncthreads();
#pragma unroll
    for (int q = 0; q < 2; ++q) {
        int pair = tid + q * 512;
        int m = pair >> 4, c = pair & 15;
        float am = a[m], th = bfreq[c];
        float e = expf(-fabsf(am));
        float sn, cs; sincosf(th, &sn, &cs);
        float gr = e * cs, gi = e * sn;
        float sre = 0.f, sim = 0.f;
        for (int r = 0; r < CH; ++r) {
            float p = pn[r][m] * rn[r];
            if (sf[r]) { sre = p; sim = 0.f; }
            else { float t = gr * sre - gi * sim + p; sim = gr * sim + gi * sre; sre = t; }
        }
        local_end[(size_t)blockIdx.x * 1024 + pair] = make_float2(sre, sim);
    }
}

// ---------------- scan phase 2 (blocks 0-15) + weight cvt (blocks 16+) ----------------
__global__ void scan_phase2w(const float2* __restrict__ local_end, const int* __restrict__ reset_any,
                             const float* __restrict__ state_re, const float* __restrict__ state_im,
                             const float* __restrict__ a, const float* __restrict__ bfreq,
                             float2* __restrict__ carry_in, float* __restrict__ out_tail, int tail_n,
                             const float* __restrict__ Wsk, const float* __restrict__ Wmx,
                             bf16* __restrict__ Bc) {
    if (blockIdx.x >= 16) {
        int idx = (blockIdx.x - 16) * 256 + threadIdx.x;  // 786432 quads
        if (idx < 262144) {                // W_skip: 1024x1024 -> Bc (coff 0)
            int r = idx >> 8, c4 = (idx & 255) << 2;
            pack4(*(const float4*)(Wsk + (size_t)r * 1024 + c4), Bc + (size_t)r * KTOT + c4);
        } else {                           // W_mix: 1024x2048 -> Bc (coff 1024)
            int i = idx - 262144;
            int r = i >> 9, c4 = (i & 511) << 2;
            pack4(*(const float4*)(Wmx + (size_t)r * 2048 + c4), Bc + (size_t)r * KTOT + 1024 + c4);
        }
        return;
    }
    if (threadIdx.x >= 64) return;
    const int pair = blockIdx.x * 64 + threadIdx.x;  // 16*64 = 1024
    const int m = pair >> 4, c = pair & 15;
    float am = a[m], th = bfreq[c];
    float e = expf(-64.f * fabsf(am));
    float sn, cs; sincosf(64.f * th, &sn, &cs);
    float gr = e * cs, gi = e * sn;
    float cre = state_re[pair], cim = state_im[pair];

    float2 pf[8]; int rsv[8];
#pragma unroll
    for (int j = 0; j < 8; ++j) { pf[j] = local_end[(size_t)j * 1024 + pair]; rsv[j] = reset_any[j]; }
    for (int kb = 0; kb < NCHUNK; kb += 8) {
        float2 cur[8]; int rs[8];
#pragma unroll
        for (int j = 0; j < 8; ++j) { cur[j] = pf[j]; rs[j] = rsv[j]; }
        if (kb + 8 < NCHUNK) {
#pragma unroll
            for (int j = 0; j < 8; ++j) {
                pf[j]  = local_end[(size_t)(kb + 8 + j) * 1024 + pair];
                rsv[j] = reset_any[kb + 8 + j];
            }
        }
#pragma unroll
        for (int j = 0; j < 8; ++j) {
            carry_in[(size_t)(kb + j) * 1024 + pair] = make_float2(cre, cim);
            if (rs[j]) { cre = cur[j].x; cim = cur[j].y; }
            else {
                float t = gr * cre - gi * cim + cur[j].x;
                cim = gr * cim + gi * cre + cur[j].y;
                cre = t;
            }
        }
    }
    if (pair < tail_n)        out_tail[pair]        = cre;
    if (1024 + pair < tail_n) out_tail[1024 + pair] = cim;
}

// ---------------- scan phase 3: 256 blocks — chunk k = b>>1, pair-half h = b&1 ----------------
__global__ void scan_phase3(const float* __restrict__ pre_raw, const int* __restrict__ start,
                            const float* __restrict__ a, const float* __restrict__ bfreq,
                            const float2* __restrict__ carry_in, bf16* __restrict__ A) {
    __shared__ float pn[CH][TRACE + 1];
    __shared__ float rn[CH];
    __shared__ int sf[CH];
    const int k = blockIdx.x >> 1, h = blockIdx.x & 1, tid = threadIdx.x;
    for (int idx = tid; idx < CH * TRACE; idx += 256) {
        int r = idx >> 6, m = idx & 63;
        pn[r][m] = pre_raw[(size_t)(k * CH + r) * TRACE + m];
    }
    if (tid < CH) sf[tid] = start[k * CH + tid];
    __syncthreads();
    if (tid < CH) {
        float s = 0.f;
#pragma unroll
        for (int m = 0; m < TRACE; ++m) { float v = pn[tid][m]; s += v * v; }
        rn[tid] = 1.0f / (1e-6f + sqrtf(s));
    }
    __syncthreads();
    {
        int p0 = h * 512 + tid * 2;           // this block covers pairs [h*512, h*512+512)
        int m = p0 >> 4, c0 = p0 & 15;
        float am = a[m];
        float e = expf(-fabsf(am));
        float sn0, cs0, sn1, cs1;
        sincosf(bfreq[c0], &sn0, &cs0);
        sincosf(bfreq[c0 + 1], &sn1, &cs1);
        float gr0 = e * cs0, gi0 = e * sn0;
        float gr1 = e * cs1, gi1 = e * sn1;
        float4 ci = *(const float4*)&carry_in[(size_t)k * 1024 + p0];
        float sre0 = ci.x, sim0 = ci.y, sre1 = ci.z, sim1 = ci.w;
        for (int r = 0; r < CH; ++r) {
            float p = pn[r][m] * rn[r];
            if (sf[r]) { sre0 = p; sim0 = 0.f; sre1 = p; sim1 = 0.f; }
            else {
                float t0 = gr0 * sre0 - gi0 * sim0 + p; sim0 = gr0 * sim0 + gi0 * sre0; sre0 = t0;
                float t1 = gr1 * sre1 - gi1 * sim1 + p; sim1 = gr1 * sim1 + gi1 * sre1; sre1 = t1;
            }
            size_t off = (size_t)(k * CH + r) * KTOT + 1024 + m * 32;
            union { bf16 h2[2]; uint32_t u; } pr, pi;
            pr.h2[0] = __float2bfloat16(sre0); pr.h2[1] = __float2bfloat16(sre1);
            pi.h2[0] = __float2bfloat16(sim0); pi.h2[1] = __float2bfloat16(sim1);
            *(uint32_t*)(A + off + c0)      = pr.u;
            *(uint32_t*)(A + off + 16 + c0) = pi.u;
        }
    }
}

// ---------------- main GEMM (r15 version — best measured) ----------------
// BM=256 BN=128 BK=64, 512 thr (8 waves 4Mx2N, 64x64/wave), grid 256 = 1 block/CU.
// 2 phases per K-tile, 3 LDS buffers:
//   phase = { ds_reads (cur) ; stage (tile u+2) ; BAR ; setprio(1) 16 MFMA setprio(0) ;
//             [vmcnt(6) at tile end] ; lgkmcnt(0) ; BAR }
__global__ __launch_bounds__(512) void gemm_main(const bf16* __restrict__ A,  // [8192][3072]
                                                 const bf16* __restrict__ B,  // [1024][3072]
                                                 const float* __restrict__ bskip,
                                                 const float* __restrict__ bmix,
                                                 float* __restrict__ out) {   // [8192][1024]
    __shared__ short As[3][256 * 64];   // 96 KB
    __shared__ short Bs[3][128 * 64];   // 48 KB
    const int tid = threadIdx.x;
    const int lane = tid & 63, wv = tid >> 6;
    const int wm = wv >> 1, wn = wv & 1;
    const int wg = blockIdx.x;
    const int xcd = wg & 7, bidx = wg >> 3;          // HW round-robins wg across XCDs
    const int row0 = (xcd * 4 + (bidx >> 3)) * 256;  // 32 row tiles
    const int col0 = (bidx & 7) * 128;               // 8 col tiles

    const int rl8 = lane >> 3;
    const int u8  = lane & 7;
    const int ksw = (u8 ^ rl8) << 3;

    auto stageBatch = [&](int su, int bd, int sb) {
#pragma unroll
        for (int jj = 0; jj < 2; ++jj) {
            int j = sb * 2 + jj;
            int r = wv * 32 + j * 8 + rl8;
            const bf16* ga = A + (size_t)(row0 + r) * KTOT + su * 64 + ksw;
            __builtin_amdgcn_global_load_lds((const AS1 void*)ga,
                (AS3 void*)&As[bd][(wv * 32 + j * 8) * 64], 16, 0, 0);
        }
        int rb = wv * 16 + sb * 8 + rl8;
        const bf16* gb = B + (size_t)(col0 + rb) * KTOT + su * 64 + ksw;
        __builtin_amdgcn_global_load_lds((const AS1 void*)gb,
            (AS3 void*)&Bs[bd][(wv * 16 + sb * 8) * 64], 16, 0, 0);
    };

    f32x4 acc[4][4];
#pragma unroll
    for (int i = 0; i < 4; ++i)
#pragma unroll
        for (int j = 0; j < 4; ++j) acc[i][j] = (f32x4)0.0f;

    const int lr = lane & 15, hi = lane >> 4;
    const int sw0 = ((0 + hi) ^ (lr & 7)) << 3;
    const int sw1 = ((4 + hi) ^ (lr & 7)) << 3;

    s16x8 af[4][2], bfr[4][2];

    auto phase = [&](int bc, int h, int su, int bd, int vm) {
        if (h == 0) {
#pragma unroll
            for (int i = 0; i < 4; ++i) {
                af[i][0] = *(const s16x8*)&As[bc][(wm * 64 + i * 16 + lr) * 64 + sw0];
                af[i][1] = *(const s16x8*)&As[bc][(wm * 64 + i * 16 + lr) * 64 + sw1];
            }
#pragma unroll
            for (int j = 0; j < 2; ++j) {
                bfr[j][0] = *(const s16x8*)&Bs[bc][(wn * 64 + j * 16 + lr) * 64 + sw0];
                bfr[j][1] = *(const s16x8*)&Bs[bc][(wn * 64 + j * 16 + lr) * 64 + sw1];
            }
        } else {
#pragma unroll
            for (int j = 2; j < 4; ++j) {
                bfr[j][0] = *(const s16x8*)&Bs[bc][(wn * 64 + j * 16 + lr) * 64 + sw0];
                bfr[j][1] = *(const s16x8*)&Bs[bc][(wn * 64 + j * 16 + lr) * 64 + sw1];
            }
        }
        if (su >= 0) stageBatch(su, bd, h);
        BAR();
        __builtin_amdgcn_s_setprio(1);
#pragma unroll
        for (int kk = 0; kk < 2; ++kk)
#pragma unroll
            for (int i = 0; i < 4; ++i)
#pragma unroll
                for (int jj = 0; jj < 2; ++jj) {
                    int j = h * 2 + jj;
                    acc[i][j] = __builtin_amdgcn_mfma_f32_16x16x32_bf16(af[i][kk], bfr[j][kk], acc[i][j], 0, 0, 0);
                }
        __builtin_amdgcn_s_setprio(0);
        if (vm == 6)      asm volatile("s_waitcnt vmcnt(6)" ::: "memory");
        else if (vm == 0) asm volatile("s_waitcnt vmcnt(0)" ::: "memory");
        asm volatile("s_waitcnt lgkmcnt(0)" ::: "memory");
        BAR();
    };

    stageBatch(0, 0, 0); stageBatch(0, 0, 1);
    stageBatch(1, 1, 0); stageBatch(1, 1, 1);
    asm volatile("s_waitcnt vmcnt(6)" ::: "memory");
    BAR();

    for (int t = 0; t < 15; ++t) {
        int u0 = 3 * t;
        phase(0, 0, u0 + 2, 2, -1);
        phase(0, 1, u0 + 2, 2,  6);
        phase(1, 0, u0 + 3, 0, -1);
        phase(1, 1, u0 + 3, 0,  6);
        phase(2, 0, u0 + 4, 1, -1);
        phase(2, 1, u0 + 4, 1,  6);
    }
    phase(0, 0, 47, 2, -1);
    phase(0, 1, 47, 2,  6);
    phase(1, 0, -1, 0, -1);
    phase(1, 1, -1, 0,  0);
    phase(2, 0, -1, 0, -1);
    phase(2, 1, -1, 0, -1);

    const int lg = lane >> 4;
#pragma unroll
    for (int j = 0; j < 4; ++j) {
        int col = col0 + wn * 64 + j * 16 + lr;
        float bias = bskip[col] + bmix[col];
#pragma unroll
        for (int i = 0; i < 4; ++i) {
            int rbase = row0 + wm * 64 + i * 16 + lg * 4;
#pragma unroll
            for (int r = 0; r < 4; ++r)
                out[(size_t)(rbase + r) * DOUT + col] = acc[i][j][r] + bias;
        }
    }
}

extern "C" void kernel_launch(void* const* d_in, const int* in_sizes, int n_in,
                              void* d_out, int out_size, void* d_ws, size_t ws_size,
                              hipStream_t stream) {
    const float* x        = (const float*)d_in[0];
    const float* state_re = (const float*)d_in[1];
    const float* state_im = (const float*)d_in[2];
    const int*   start    = (const int*)d_in[3];
    const float* W_pre    = (const float*)d_in[5];
    const float* b_pre    = (const float*)d_in[6];
    const float* W_skip   = (const float*)d_in[7];
    const float* b_skip   = (const float*)d_in[8];
    const float* W_mix    = (const float*)d_in[9];
    const float* b_mix    = (const float*)d_in[10];
    const float* a_dec    = (const float*)d_in[11];
    const float* b_freq   = (const float*)d_in[12];

    uint8_t* ws = (uint8_t*)d_ws;
    bf16*  A         = (bf16*)(ws);                 // 50331648
    bf16*  Bc        = (bf16*)(ws + 50331648);      // 6291456
    bf16*  Wp        = (bf16*)(ws + 56623104);      // 131072
    float* pre_raw   = (float*)(ws + 56754176);     // 2097152
    float2* local_end= (float2*)(ws + 58851328);    // 1048576
    float2* carry_in = (float2*)(ws + 59899904);    // 1048576
    int*   reset_any = (int*)(ws + 60948480);       // 512

    cvt_x<<<dim3((2113536 + 255) / 256), 256, 0, stream>>>(x, W_pre, A, Wp);

    pre_scan1<<<dim3(NCHUNK), 512, 0, stream>>>(A, Wp, b_pre, start, a_dec, b_freq,
                                                pre_raw, local_end, reset_any);
    int tail_n = out_size - 8192 * 1024;
    if (tail_n < 0) tail_n = 0;
    if (tail_n > 2048) tail_n = 2048;
    scan_phase2w<<<dim3(16 + 3072), 256, 0, stream>>>(local_end, reset_any, state_re, state_im,
                                                      a_dec, b_freq, carry_in,
                                                      (float*)d_out + 8192 * 1024, tail_n,
                                                      W_skip, W_mix, Bc);
    scan_phase3<<<dim3(2 * NCHUNK), 256, 0, stream>>>(pre_raw, start, a_dec, b_freq, carry_in, A);

    gemm_main<<<dim3(256), 512, 0, stream>>>(A, Bc, b_skip, b_mix, (float*)d_out);
}

// Round 22
// 111.314 us; speedup vs baseline: 1.1127x; 1.0084x over previous
//
#include <hip/hip_runtime.h>
#include <hip/hip_bf16.h>
#include <stdint.h>

#define T_LEN 8192
#define DIN   1024
#define DOUT  1024
#define TRACE 64
#define CTX   16
#define KTOT  3072      // DIN + 2*TRACE*CTX
#define CH    64        // scan chunk length
#define NCHUNK 128      // T_LEN / CH

#define AS1 __attribute__((address_space(1)))
#define AS3 __attribute__((address_space(3)))

// Compile-time-fenced barrier (r9 race fix: intrinsic barrier is not a compiler fence).
#define BAR() asm volatile("s_barrier" ::: "memory")

using bf16 = __hip_bfloat16;
typedef __attribute__((ext_vector_type(4))) float f32x4;
typedef __attribute__((ext_vector_type(8))) short s16x8;

__device__ __forceinline__ void pack4(const float4 v, void* dst) {
    union { bf16 h[4]; uint2 u; } pk;
    pk.h[0] = __float2bfloat16(v.x); pk.h[1] = __float2bfloat16(v.y);
    pk.h[2] = __float2bfloat16(v.z); pk.h[3] = __float2bfloat16(v.w);
    *(uint2*)dst = pk.u;
}

// ---------------- f32 -> bf16: x and W_pre, grid-stride (2048 blocks) ----------------
__global__ void cvt_x(const float* __restrict__ x, const float* __restrict__ Wpre,
                      bf16* __restrict__ A, bf16* __restrict__ Wp) {
    const int stride = gridDim.x * 256;
    for (int idx = blockIdx.x * 256 + threadIdx.x; idx < 2113536; idx += stride) {
        if (idx < 2097152) {                   // x: 8192x1024 -> A (ld 3072)
            int r = idx >> 8, c4 = (idx & 255) << 2;
            pack4(*(const float4*)(x + (size_t)r * 1024 + c4), A + (size_t)r * KTOT + c4);
        } else {                               // W_pre: 64x1024 -> Wp (ld 1024)
            int i = idx - 2097152;
            int r = i >> 8, c4 = (i & 255) << 2;
            pack4(*(const float4*)(Wpre + (size_t)r * 1024 + c4), Wp + (size_t)r * 1024 + c4);
        }
    }
}

// ---------------- fused pre-GEMM + scan phase 1 — 512 threads (8 waves, r20) ----------------
__global__ __launch_bounds__(512) void pre_scan1(
    const bf16* __restrict__ A,     // [8192][KTOT], x part (k<1024)
    const bf16* __restrict__ Wp,    // [64][1024]
    const float* __restrict__ bpre,
    const int* __restrict__ start,
    const float* __restrict__ a, const float* __restrict__ bfreq,
    float* __restrict__ pre_raw,    // [8192][64]
    float2* __restrict__ local_end, // [128][1024]
    int* __restrict__ reset_any) {  // [128]
    __shared__ short As[2][64 * 32];
    __shared__ short Bs[2][64 * 32];
    __shared__ float pn[CH][TRACE + 1];
    __shared__ float rn[CH];
    __shared__ int sf[CH];
    const int tid = threadIdx.x, lane = tid & 63, wv = tid >> 6;   // 8 waves
    const int row0 = blockIdx.x * 64;
    const int l4 = lane >> 2, c8 = (lane & 3) * 8;
    const int wm = wv & 3, wn = wv >> 2;

    auto stage = [&](int kt, int buf) {
        if (wv < 4) {
            int r = wv * 16 + l4;
            const bf16* ga = A + (size_t)(row0 + r) * KTOT + kt * 32 + c8;
            __builtin_amdgcn_global_load_lds(
                (const AS1 void*)ga, (AS3 void*)&As[buf][wv * 512], 16, 0, 0);
        } else {
            int r = (wv - 4) * 16 + l4;
            const bf16* gb = Wp + (size_t)r * 1024 + kt * 32 + c8;
            __builtin_amdgcn_global_load_lds(
                (const AS1 void*)gb, (AS3 void*)&Bs[buf][(wv - 4) * 512], 16, 0, 0);
        }
    };

    f32x4 acc[2];
#pragma unroll
    for (int j = 0; j < 2; ++j) acc[j] = (f32x4)0.0f;

    stage(0, 0);
    __syncthreads();
    int buf = 0;
    const int lr = lane & 15, lk = (lane >> 4) * 8;
    for (int kt = 0; kt < 32; ++kt) {
        if (kt + 1 < 32) stage(kt + 1, buf ^ 1);
        s16x8 af = *(const s16x8*)&As[buf][(wm * 16 + lr) * 32 + lk];
        s16x8 bfr[2];
#pragma unroll
        for (int j = 0; j < 2; ++j)
            bfr[j] = *(const s16x8*)&Bs[buf][(wn * 32 + j * 16 + lr) * 32 + lk];
#pragma unroll
        for (int j = 0; j < 2; ++j)
            acc[j] = __builtin_amdgcn_mfma_f32_16x16x32_bf16(af, bfr[j], acc[j], 0, 0, 0);
        __syncthreads();
        buf ^= 1;
    }
    const int lg = lane >> 4;
#pragma unroll
    for (int j = 0; j < 2; ++j) {
        int col = wn * 32 + j * 16 + lr;
        float bias = bpre[col];
#pragma unroll
        for (int r = 0; r < 4; ++r) {
            int rl = wm * 16 + lg * 4 + r;
            float v = acc[j][r] + bias;
            pn[rl][col] = v;
            pre_raw[(size_t)(row0 + rl) * TRACE + col] = v;
        }
    }
    if (tid < CH) sf[tid] = start[row0 + tid];
    __syncthreads();
    if (tid < CH) {
        float s = 0.f;
#pragma unroll
        for (int m = 0; m < TRACE; ++m) { float v = pn[tid][m]; s += v * v; }
        rn[tid] = 1.0f / (1e-6f + sqrtf(s));
        int any = __any(sf[tid] != 0);
        if (tid == 0) reset_any[blockIdx.x] = any;
    }
    __syncthreads();
#pragma unroll
    for (int q = 0; q < 2; ++q) {
        int pair = tid + q * 512;
        int m = pair >> 4, c = pair & 15;
        float am = a[m], th = bfreq[c];
        float e = expf(-fabsf(am));
        float sn, cs; sincosf(th, &sn, &cs);
        float gr = e * cs, gi = e * sn;
        float sre = 0.f, sim = 0.f;
        for (int r = 0; r < CH; ++r) {
            float p = pn[r][m] * rn[r];
            if (sf[r]) { sre = p; sim = 0.f; }
            else { float t = gr * sre - gi * sim + p; sim = gr * sim + gi * sre; sre = t; }
        }
        local_end[(size_t)blockIdx.x * 1024 + pair] = make_float2(sre, sim);
    }
}

// ---------------- scan phase 2 (blocks 0-15) + weight cvt (blocks 16+) ----------------
__global__ void scan_phase2w(const float2* __restrict__ local_end, const int* __restrict__ reset_any,
                             const float* __restrict__ state_re, const float* __restrict__ state_im,
                             const float* __restrict__ a, const float* __restrict__ bfreq,
                             float2* __restrict__ carry_in, float* __restrict__ out_tail, int tail_n,
                             const float* __restrict__ Wsk, const float* __restrict__ Wmx,
                             bf16* __restrict__ Bc) {
    if (blockIdx.x >= 16) {
        int idx = (blockIdx.x - 16) * 256 + threadIdx.x;  // 786432 quads
        if (idx < 262144) {                // W_skip: 1024x1024 -> Bc (coff 0)
            int r = idx >> 8, c4 = (idx & 255) << 2;
            pack4(*(const float4*)(Wsk + (size_t)r * 1024 + c4), Bc + (size_t)r * KTOT + c4);
        } else {                           // W_mix: 1024x2048 -> Bc (coff 1024)
            int i = idx - 262144;
            int r = i >> 9, c4 = (i & 511) << 2;
            pack4(*(const float4*)(Wmx + (size_t)r * 2048 + c4), Bc + (size_t)r * KTOT + 1024 + c4);
        }
        return;
    }
    if (threadIdx.x >= 64) return;
    const int pair = blockIdx.x * 64 + threadIdx.x;  // 16*64 = 1024
    const int m = pair >> 4, c = pair & 15;
    float am = a[m], th = bfreq[c];
    float e = expf(-64.f * fabsf(am));
    float sn, cs; sincosf(64.f * th, &sn, &cs);
    float gr = e * cs, gi = e * sn;
    float cre = state_re[pair], cim = state_im[pair];

    float2 pf[8]; int rsv[8];
#pragma unroll
    for (int j = 0; j < 8; ++j) { pf[j] = local_end[(size_t)j * 1024 + pair]; rsv[j] = reset_any[j]; }
    for (int kb = 0; kb < NCHUNK; kb += 8) {
        float2 cur[8]; int rs[8];
#pragma unroll
        for (int j = 0; j < 8; ++j) { cur[j] = pf[j]; rs[j] = rsv[j]; }
        if (kb + 8 < NCHUNK) {
#pragma unroll
            for (int j = 0; j < 8; ++j) {
                pf[j]  = local_end[(size_t)(kb + 8 + j) * 1024 + pair];
                rsv[j] = reset_any[kb + 8 + j];
            }
        }
#pragma unroll
        for (int j = 0; j < 8; ++j) {
            carry_in[(size_t)(kb + j) * 1024 + pair] = make_float2(cre, cim);
            if (rs[j]) { cre = cur[j].x; cim = cur[j].y; }
            else {
                float t = gr * cre - gi * cim + cur[j].x;
                cim = gr * cim + gi * cre + cur[j].y;
                cre = t;
            }
        }
    }
    if (pair < tail_n)        out_tail[pair]        = cre;
    if (1024 + pair < tail_n) out_tail[1024 + pair] = cim;
}

// ---------------- scan phase 3: 256 blocks — chunk k = b>>1, pair-half h = b&1 ----------------
// 128 ACTIVE threads: thread covers (m, c0..c0+3), m = h*32 + (tid>>2), c0 = (tid&3)*4.
// (r21 bug: 256 threads overran m to 95 -> OOB writes into next row's x-columns.)
__global__ void scan_phase3(const float* __restrict__ pre_raw, const int* __restrict__ start,
                            const float* __restrict__ a, const float* __restrict__ bfreq,
                            const float2* __restrict__ carry_in, bf16* __restrict__ A) {
    __shared__ float pn[CH][TRACE + 1];
    __shared__ float rn[CH];
    __shared__ int sf[CH];
    const int k = blockIdx.x >> 1, h = blockIdx.x & 1, tid = threadIdx.x;
    // staged load: 64 rows x 16 float4 = 1024 quads, 256 threads -> 4 iters
    for (int q4 = tid; q4 < CH * 16; q4 += 256) {
        int r = q4 >> 4, c4 = (q4 & 15) << 2;
        float4 v = *(const float4*)(pre_raw + (size_t)(k * CH + r) * TRACE + c4);
        pn[r][c4] = v.x; pn[r][c4 + 1] = v.y; pn[r][c4 + 2] = v.z; pn[r][c4 + 3] = v.w;
    }
    if (tid < CH) sf[tid] = start[k * CH + tid];
    __syncthreads();
    if (tid < CH) {
        float s = 0.f;
#pragma unroll
        for (int m = 0; m < TRACE; ++m) { float v = pn[tid][m]; s += v * v; }
        rn[tid] = 1.0f / (1e-6f + sqrtf(s));
    }
    __syncthreads();
    if (tid < 128) {
        int m  = h * 32 + (tid >> 2);         // 32 m-values per half
        int c0 = (tid & 3) * 4;               // 4 consecutive c per thread
        float am = a[m];
        float e = expf(-fabsf(am));
        float gr[4], gi[4], sre[4], sim[4];
#pragma unroll
        for (int j = 0; j < 4; ++j) {
            float sn, cs; sincosf(bfreq[c0 + j], &sn, &cs);
            gr[j] = e * cs; gi[j] = e * sn;
        }
        float4 ci0 = *(const float4*)&carry_in[(size_t)k * 1024 + m * 16 + c0];
        float4 ci1 = *(const float4*)&carry_in[(size_t)k * 1024 + m * 16 + c0 + 2];
        sre[0] = ci0.x; sim[0] = ci0.y; sre[1] = ci0.z; sim[1] = ci0.w;
        sre[2] = ci1.x; sim[2] = ci1.y; sre[3] = ci1.z; sim[3] = ci1.w;
        for (int r = 0; r < CH; ++r) {
            float p = pn[r][m] * rn[r];
            if (sf[r]) {
#pragma unroll
                for (int j = 0; j < 4; ++j) { sre[j] = p; sim[j] = 0.f; }
            } else {
#pragma unroll
                for (int j = 0; j < 4; ++j) {
                    float t = gr[j] * sre[j] - gi[j] * sim[j] + p;
                    sim[j] = gr[j] * sim[j] + gi[j] * sre[j];
                    sre[j] = t;
                }
            }
            size_t off = (size_t)(k * CH + r) * KTOT + 1024 + m * 32;
            union { bf16 hh[4]; uint2 u; } pr, pi;
#pragma unroll
            for (int j = 0; j < 4; ++j) { pr.hh[j] = __float2bfloat16(sre[j]); pi.hh[j] = __float2bfloat16(sim[j]); }
            *(uint2*)(A + off + c0)      = pr.u;
            *(uint2*)(A + off + 16 + c0) = pi.u;
        }
    }
}

// ---------------- main GEMM (r15 version — best measured) ----------------
// BM=256 BN=128 BK=64, 512 thr (8 waves 4Mx2N, 64x64/wave), grid 256 = 1 block/CU.
// 2 phases per K-tile, 3 LDS buffers:
//   phase = { ds_reads (cur) ; stage (tile u+2) ; BAR ; setprio(1) 16 MFMA setprio(0) ;
//             [vmcnt(6) at tile end] ; lgkmcnt(0) ; BAR }
__global__ __launch_bounds__(512) void gemm_main(const bf16* __restrict__ A,  // [8192][3072]
                                                 const bf16* __restrict__ B,  // [1024][3072]
                                                 const float* __restrict__ bskip,
                                                 const float* __restrict__ bmix,
                                                 float* __restrict__ out) {   // [8192][1024]
    __shared__ short As[3][256 * 64];   // 96 KB
    __shared__ short Bs[3][128 * 64];   // 48 KB
    const int tid = threadIdx.x;
    const int lane = tid & 63, wv = tid >> 6;
    const int wm = wv >> 1, wn = wv & 1;
    const int wg = blockIdx.x;
    const int xcd = wg & 7, bidx = wg >> 3;          // HW round-robins wg across XCDs
    const int row0 = (xcd * 4 + (bidx >> 3)) * 256;  // 32 row tiles
    const int col0 = (bidx & 7) * 128;               // 8 col tiles

    const int rl8 = lane >> 3;
    const int u8  = lane & 7;
    const int ksw = (u8 ^ rl8) << 3;

    auto stageBatch = [&](int su, int bd, int sb) {
#pragma unroll
        for (int jj = 0; jj < 2; ++jj) {
            int j = sb * 2 + jj;
            int r = wv * 32 + j * 8 + rl8;
            const bf16* ga = A + (size_t)(row0 + r) * KTOT + su * 64 + ksw;
            __builtin_amdgcn_global_load_lds((const AS1 void*)ga,
                (AS3 void*)&As[bd][(wv * 32 + j * 8) * 64], 16, 0, 0);
        }
        int rb = wv * 16 + sb * 8 + rl8;
        const bf16* gb = B + (size_t)(col0 + rb) * KTOT + su * 64 + ksw;
        __builtin_amdgcn_global_load_lds((const AS1 void*)gb,
            (AS3 void*)&Bs[bd][(wv * 16 + sb * 8) * 64], 16, 0, 0);
    };

    f32x4 acc[4][4];
#pragma unroll
    for (int i = 0; i < 4; ++i)
#pragma unroll
        for (int j = 0; j < 4; ++j) acc[i][j] = (f32x4)0.0f;

    const int lr = lane & 15, hi = lane >> 4;
    const int sw0 = ((0 + hi) ^ (lr & 7)) << 3;
    const int sw1 = ((4 + hi) ^ (lr & 7)) << 3;

    s16x8 af[4][2], bfr[4][2];

    auto phase = [&](int bc, int h, int su, int bd, int vm) {
        if (h == 0) {
#pragma unroll
            for (int i = 0; i < 4; ++i) {
                af[i][0] = *(const s16x8*)&As[bc][(wm * 64 + i * 16 + lr) * 64 + sw0];
                af[i][1] = *(const s16x8*)&As[bc][(wm * 64 + i * 16 + lr) * 64 + sw1];
            }
#pragma unroll
            for (int j = 0; j < 2; ++j) {
                bfr[j][0] = *(const s16x8*)&Bs[bc][(wn * 64 + j * 16 + lr) * 64 + sw0];
                bfr[j][1] = *(const s16x8*)&Bs[bc][(wn * 64 + j * 16 + lr) * 64 + sw1];
            }
        } else {
#pragma unroll
            for (int j = 2; j < 4; ++j) {
                bfr[j][0] = *(const s16x8*)&Bs[bc][(wn * 64 + j * 16 + lr) * 64 + sw0];
                bfr[j][1] = *(const s16x8*)&Bs[bc][(wn * 64 + j * 16 + lr) * 64 + sw1];
            }
        }
        if (su >= 0) stageBatch(su, bd, h);
        BAR();
        __builtin_amdgcn_s_setprio(1);
#pragma unroll
        for (int kk = 0; kk < 2; ++kk)
#pragma unroll
            for (int i = 0; i < 4; ++i)
#pragma unroll
                for (int jj = 0; jj < 2; ++jj) {
                    int j = h * 2 + jj;
                    acc[i][j] = __builtin_amdgcn_mfma_f32_16x16x32_bf16(af[i][kk], bfr[j][kk], acc[i][j], 0, 0, 0);
                }
        __builtin_amdgcn_s_setprio(0);
        if (vm == 6)      asm volatile("s_waitcnt vmcnt(6)" ::: "memory");
        else if (vm == 0) asm volatile("s_waitcnt vmcnt(0)" ::: "memory");
        asm volatile("s_waitcnt lgkmcnt(0)" ::: "memory");
        BAR();
    };

    stageBatch(0, 0, 0); stageBatch(0, 0, 1);
    stageBatch(1, 1, 0); stageBatch(1, 1, 1);
    asm volatile("s_waitcnt vmcnt(6)" ::: "memory");
    BAR();

    for (int t = 0; t < 15; ++t) {
        int u0 = 3 * t;
        phase(0, 0, u0 + 2, 2, -1);
        phase(0, 1, u0 + 2, 2,  6);
        phase(1, 0, u0 + 3, 0, -1);
        phase(1, 1, u0 + 3, 0,  6);
        phase(2, 0, u0 + 4, 1, -1);
        phase(2, 1, u0 + 4, 1,  6);
    }
    phase(0, 0, 47, 2, -1);
    phase(0, 1, 47, 2,  6);
    phase(1, 0, -1, 0, -1);
    phase(1, 1, -1, 0,  0);
    phase(2, 0, -1, 0, -1);
    phase(2, 1, -1, 0, -1);

    const int lg = lane >> 4;
#pragma unroll
    for (int j = 0; j < 4; ++j) {
        int col = col0 + wn * 64 + j * 16 + lr;
        float bias = bskip[col] + bmix[col];
#pragma unroll
        for (int i = 0; i < 4; ++i) {
            int rbase = row0 + wm * 64 + i * 16 + lg * 4;
#pragma unroll
            for (int r = 0; r < 4; ++r)
                out[(size_t)(rbase + r) * DOUT + col] = acc[i][j][r] + bias;
        }
    }
}

extern "C" void kernel_launch(void* const* d_in, const int* in_sizes, int n_in,
                              void* d_out, int out_size, void* d_ws, size_t ws_size,
                              hipStream_t stream) {
    const float* x        = (const float*)d_in[0];
    const float* state_re = (const float*)d_in[1];
    const float* state_im = (const float*)d_in[2];
    const int*   start    = (const int*)d_in[3];
    const float* W_pre    = (const float*)d_in[5];
    const float* b_pre    = (const float*)d_in[6];
    const float* W_skip   = (const float*)d_in[7];
    const float* b_skip   = (const float*)d_in[8];
    const float* W_mix    = (const float*)d_in[9];
    const float* b_mix    = (const float*)d_in[10];
    const float* a_dec    = (const float*)d_in[11];
    const float* b_freq   = (const float*)d_in[12];

    uint8_t* ws = (uint8_t*)d_ws;
    bf16*  A         = (bf16*)(ws);                 // 50331648
    bf16*  Bc        = (bf16*)(ws + 50331648);      // 6291456
    bf16*  Wp        = (bf16*)(ws + 56623104);      // 131072
    float* pre_raw   = (float*)(ws + 56754176);     // 2097152
    float2* local_end= (float2*)(ws + 58851328);    // 1048576
    float2* carry_in = (float2*)(ws + 59899904);    // 1048576
    int*   reset_any = (int*)(ws + 60948480);       // 512

    cvt_x<<<dim3(2048), 256, 0, stream>>>(x, W_pre, A, Wp);

    pre_scan1<<<dim3(NCHUNK), 512, 0, stream>>>(A, Wp, b_pre, start, a_dec, b_freq,
                                                pre_raw, local_end, reset_any);
    int tail_n = out_size - 8192 * 1024;
    if (tail_n < 0) tail_n = 0;
    if (tail_n > 2048) tail_n = 2048;
    scan_phase2w<<<dim3(16 + 3072), 256, 0, stream>>>(local_end, reset_any, state_re, state_im,
                                                      a_dec, b_freq, carry_in,
                                                      (float*)d_out + 8192 * 1024, tail_n,
                                                      W_skip, W_mix, Bc);
    scan_phase3<<<dim3(2 * NCHUNK), 256, 0, stream>>>(pre_raw, start, a_dec, b_freq, carry_in, A);

    gemm_main<<<dim3(256), 512, 0, stream>>>(A, Bc, b_skip, b_mix, (float*)d_out);
}